// Round 11
// baseline (207.756 us; speedup 1.0000x reference)
//
#include <hip/hip_runtime.h>
#include <math.h>

// ---------------------------------------------------------------------------
// SO3 convolution. bf16 MFMA GEMM (complex-as-real); Hermitian-half FFT/IFFT.
// Pipeline: k_fft_fwd -> k_wtr(wf) -> k_prep_B -> k_beta_A
//           -> k_gemm (MFMA) -> k_wtr(wi) -> k_inv2
// R8 lesson: fusing fft+prep spilled -- keep kernels separate.
// R9: wfT/wiT [bq][t][4] transposes -- big win in k_beta_A.
// R10: k_inv2 streamed FFT passes (VGPR 92->64), 8 blocks/CU -- 68->~40us.
// R11 NEUTRAL: depth-1 prefetch didn't move k_gemm.
// R12: yhb in MFMA-fragment order; k_gemm no-LDS no-barrier -- ~49us.
// R13: o-quarter split, 1024 blocks -- Occ 13->27%, -12% time only.
// R14: k_inv2 packed-fp32 complex math + register twiddle chains -- <42us.
// R15 DISASTER (155us): scattered unsafeAtomicAdd. R16 REGRESSION (70us):
// two partial buffers = write-allocate RMW. Scattered-store reductions are
// poison in ANY form.
// R17 BROKEN (tail double-count). R18 = fixed distance-4 pipeline: NEUTRAL
// (202us) -> k_gemm is NOT latency-bound. Traffic audit: A-panel depends
// only on (l,step); 4nl siblings re-stream it -> ~349MB A + 44MB B through
// L3 at 43us ~ 9TB/s = L3-BW roofline. That explains all neutral results.
// R19: XCD-COHORT swizzle: xcd=id&7, oq=(id>>3)&3, g=(id>>5)*8+xcd ->
// the 4 oq-siblings of (l,n) + ~4 same-l groups land on ONE XCD, adjacent
// launch -> A served from that XCD's L2 (<=34MB from L3 total, was 349MB).
// All 1024 blocks co-resident (4/CU) so placement alone decides sharing.
// Workspace: yhb 44.7MB | Ab 4.2MB | zh_T 11.2MB.
//   Xfb (8.4MB) + wfT (698KB) alias zh_T (lifetime fft->gemm, disjoint).
//   wiT (698KB) aliases yhb base (written after gemm, read by inv2).
// ---------------------------------------------------------------------------

typedef unsigned short u16;
typedef unsigned int   u32;
typedef __attribute__((ext_vector_type(8))) short  short8;   // 8 bf16
typedef __attribute__((ext_vector_type(4))) float  floatx4;
typedef __attribute__((ext_vector_type(2))) float  f32x2;

constexpr int LTOT = 5456;

constexpr int LB[17] = {0,1,10,35,84,165,286,455,680,969,
                        1330,1771,2300,2925,3654,4495,5456};

__device__ inline u16 f2bf(float f) {
    u32 u = __float_as_uint(f);
    u += 0x7fff + ((u >> 16) & 1);
    return (u16)(u >> 16);
}
__device__ inline u32 pack2bf(float re, float im) {
    return (u32)f2bf(re) | ((u32)f2bf(im) << 16);
}

// cc-dependent complex pack transform: cc=0 -> (re,-im) == b ^ 0x80000000;
// cc=1 -> (im,re) == ror16(b). Done as per-lane-constant perm + xor.
__device__ inline short8 btr4(uint4 q, u32 sel, u32 msk) {
    uint4 t;
    t.x = __builtin_amdgcn_perm(q.x, q.x, sel) ^ msk;
    t.y = __builtin_amdgcn_perm(q.y, q.y, sel) ^ msk;
    t.z = __builtin_amdgcn_perm(q.z, q.z, sel) ^ msk;
    t.w = __builtin_amdgcn_perm(q.w, q.w, sel) ^ msk;
    return *(short8*)&t;
}

// ---- packed-fp32 complex helpers (VOP3P). acc/result = (re, im) pairs. ----
__device__ __forceinline__ f32x2 cfma(f32x2 e, f32x2 t, f32x2 acc) {
    asm("v_pk_fma_f32 %0, %1, %2, %0 op_sel:[0,0,0] op_sel_hi:[0,1,1]\n\t"
        "v_pk_fma_f32 %0, %1, %2, %0 op_sel:[1,1,0] op_sel_hi:[1,0,1] neg_lo:[0,1,0]"
        : "+v"(acc) : "v"(e), "v"(t));
    return acc;
}
__device__ __forceinline__ f32x2 cmulp(f32x2 t, f32x2 r) {
    f32x2 d;
    asm("v_pk_mul_f32 %0, %1, %2 op_sel:[0,0] op_sel_hi:[0,1]\n\t"
        "v_pk_fma_f32 %0, %1, %2, %0 op_sel:[1,1,0] op_sel_hi:[1,0,1] neg_lo:[0,1,0]"
        : "=&v"(d) : "v"(t), "v"(r));
    return d;
}
__device__ __forceinline__ f32x2 fma_bl(f32x2 w2, f32x2 v, f32x2 acc) {
    asm("v_pk_fma_f32 %0, %1, %2, %0 op_sel:[0,0,0] op_sel_hi:[0,1,1]"
        : "+v"(acc) : "v"(w2), "v"(v));
    return acc;
}
__device__ __forceinline__ f32x2 fma_bh(f32x2 w2, f32x2 v, f32x2 acc) {
    asm("v_pk_fma_f32 %0, %1, %2, %0 op_sel:[1,0,0] op_sel_hi:[1,1,1]"
        : "+v"(acc) : "v"(w2), "v"(v));
    return acc;
}

// ---------------------------------------------------------------------------
// Wigner-table transpose: w[32][LTOT] -> wT[bq(8)][t][4] so a 4-beta group is
// one float4. Grid (22, 8) x 256.
// ---------------------------------------------------------------------------
__global__ __launch_bounds__(256) void k_wtr(const float* __restrict__ w,
                                             float* __restrict__ wT) {
    int t  = blockIdx.x * 256 + threadIdx.x;
    int bq = blockIdx.y;
    if (t < LTOT) {
        float4 v;
        v.x = w[(size_t)(bq * 4 + 0) * LTOT + t];
        v.y = w[(size_t)(bq * 4 + 1) * LTOT + t];
        v.z = w[(size_t)(bq * 4 + 2) * LTOT + t];
        v.w = w[(size_t)(bq * 4 + 3) * LTOT + t];
        *(float4*)(wT + ((size_t)bq * LTOT + t) * 4) = v;
    }
}

// ---------------------------------------------------------------------------
// Forward FFT2 (e^{-i}), radix-2 both passes, 512 threads, one task each.
// Stores ONLY Hermitian-half rows ma 0..15, bf16-packed.
// x: [z][i][b][a][g].   Xfb: [zi*32+b][ma(0..15)][ng] packed bf16 pairs.
// ---------------------------------------------------------------------------
__global__ __launch_bounds__(512) void k_fft_fwd(const float* __restrict__ x,
                                                 u32* __restrict__ Xfb) {
    __shared__ float xs[1056];               // [a][g] stride 33
    __shared__ float Gre[1056], Gim[1056];   // [a][k] stride 33
    __shared__ float Wc[32], Ws[32];
    int tid = threadIdx.x;
    if (tid < 32) {
        float sv, cv;
        sincosf(6.28318530717958647692f * (float)tid / 32.0f, &sv, &cv);
        Wc[tid] = cv; Ws[tid] = sv;
    }
    const float* src = x + (size_t)blockIdx.x * 1024;
    for (int e = tid; e < 1024; e += 512) xs[(e >> 5) * 33 + (e & 31)] = src[e];
    __syncthreads();
    // pass 1 over g (real input), radix-2: task = (a, k in 0..15)
    {
        int a = tid >> 4, k = tid & 15;
        const float* row = &xs[a * 33];
        float Er = 0.f, Ei = 0.f, Or = 0.f, Oi = 0.f;
#pragma unroll
        for (int h = 0; h < 16; h++) {
            int idx = (2 * h * k) & 31;
            float c = Wc[idx], s = Ws[idx];
            float xe = row[2 * h], xo = row[2 * h + 1];
            Er += xe * c;  Ei -= xe * s;
            Or += xo * c;  Oi -= xo * s;
        }
        float WOr = Or * Wc[k] + Oi * Ws[k];
        float WOi = Oi * Wc[k] - Or * Ws[k];
        Gre[a * 33 + k]      = Er + WOr;
        Gim[a * 33 + k]      = Ei + WOi;
        Gre[a * 33 + k + 16] = Er - WOr;
        Gim[a * 33 + k + 16] = Ei - WOi;
    }
    __syncthreads();
    // pass 2 over a, radix-2 combine; store only row ma (0..15)
    {
        u32* dst = Xfb + (size_t)blockIdx.x * 512;
        int ng = tid & 31, ma = tid >> 5;
        float Er = 0.f, Ei = 0.f, Or = 0.f, Oi = 0.f;
#pragma unroll
        for (int h = 0; h < 16; h++) {
            int idx = (2 * h * ma) & 31;
            float c = Wc[idx], s = Ws[idx];
            float er = Gre[(2 * h) * 33 + ng],      ei = Gim[(2 * h) * 33 + ng];
            float orr = Gre[(2 * h + 1) * 33 + ng], oi = Gim[(2 * h + 1) * 33 + ng];
            Er += er * c + ei * s;   Ei += ei * c - er * s;
            Or += orr * c + oi * s;  Oi += oi * c - orr * s;
        }
        float WOr = Or * Wc[ma] + Oi * Ws[ma];
        float WOi = Oi * Wc[ma] - Or * Ws[ma];
        dst[ma * 32 + ng] = pack2bf(Er + WOr, Ei + WOi);
    }
}

// ---------------------------------------------------------------------------
// Build compact bf16 yh in MFMA-FRAGMENT ORDER (R12):
// io = (i,o): i = ih*16+kh*4+j, o = oh*32+nt*8+ph
// nio = ih*1024 + oh*512 + nt*128 + kh*32 + ph*4 + j
// so k_gemm's lane fragment (4 words j=0..3) is one contiguous uint4.
// ---------------------------------------------------------------------------
__global__ __launch_bounds__(256) void k_prep_B(const float* __restrict__ Dre,
                                                const float* __restrict__ Dim,
                                                const float* __restrict__ ker,
                                                u32* __restrict__ yhb) {
    __shared__ float Ds[8][24];
    int t0  = blockIdx.x * 8;
    int tid = threadIdx.x;
    if (tid < 192) {
        int rr = tid / 24, jj = tid - rr * 24;
        Ds[rr][jj] = (jj < 12) ? Dre[(t0 + rr) * 12 + jj] : Dim[(t0 + rr) * 12 + jj - 12];
    }
    __syncthreads();
    for (int rep = 0; rep < 8; rep++) {
        int io = rep * 256 + tid;
        int i  = io >> 6, o = io & 63;
        int nio = ((i >> 4) << 10) + ((o >> 5) << 9) + (((o >> 3) & 3) << 7)
                + (((i >> 2) & 3) << 5) + ((o & 7) << 2) + (i & 3);
        const float4* kp = (const float4*)(ker + io * 12);
        float4 ka = kp[0], kb = kp[1], kc = kp[2];
        float kv[12] = {ka.x, ka.y, ka.z, ka.w, kb.x, kb.y, kb.z, kb.w,
                        kc.x, kc.y, kc.z, kc.w};
#pragma unroll
        for (int rr = 0; rr < 8; rr++) {
            float sr = 0.f, si = 0.f;
#pragma unroll
            for (int j = 0; j < 12; j++) {
                sr += Ds[rr][j]      * kv[j];
                si += Ds[rr][12 + j] * kv[j];
            }
            yhb[(size_t)(t0 + rr) * 2048 + nio] = pack2bf(sr, si);
        }
    }
}

// ---------------------------------------------------------------------------
// Fused beta-contraction + bf16 A-fragment pack. Xfb is Hermitian-half:
// rows ma 0..15 stored; ma>=17 read as conj(Xf[32-ma][(32-ng)&31]).
// Grid: (ma 32) x (zig 64) = 2048 blocks; thread = (zil 2, lq 4, ng 32).
// R9: b-loop grouped in beta-quads; wfT[bq][t][4] gives one float4 per
// (bq, l) instead of 4 scalar strided loads.
// ---------------------------------------------------------------------------
__global__ __launch_bounds__(256) void k_beta_A(const u32* __restrict__ Xfb,
                                                const float* __restrict__ wfT,
                                                u16* __restrict__ Ab) {
    int ma  = blockIdx.x >> 6;
    int zig = blockIdx.x & 63;
    int tid = threadIdx.x;
    int ng  = tid & 31;
    int lq  = (tid >> 5) & 3;
    int zil = tid >> 7;
    int zi  = zig * 2 + zil;
    int z = zi >> 5, i = zi & 31;
    int mh = (ma <= 15) ? ma : ma - 32;
    int nh = (ng <= 15) ? ng : ng - 32;
    int am = mh < 0 ? -mh : mh;
    int an = nh < 0 ? -nh : nh;
    int l0 = am > an ? am : an;
    int lb = lq * 4;

    int isconj = (ma > 16);
    int mau = isconj ? (32 - ma) : ma;
    int ngu = isconj ? ((32 - ng) & 31) : ng;
    if (mau > 15) { mau = 0; ngu = 0; }   // ma==16: l0==16, values unused

    int tl[4];
#pragma unroll
    for (int j = 0; j < 4; j++) {
        int l = lb + j;
        tl[j] = LB[l] + (mh + l) * (2 * l + 1) + (nh + l);
    }
    float2 acc[4];
#pragma unroll
    for (int j = 0; j < 4; j++) acc[j] = make_float2(0.f, 0.f);

    const u32* xp = Xfb + (size_t)zi * 32 * 512 + mau * 32 + ngu;
    float sgn = isconj ? -1.f : 1.f;
#pragma unroll 2
    for (int bq = 0; bq < 8; bq++) {
        u32 p0 = xp[(size_t)(4 * bq + 0) * 512];
        u32 p1 = xp[(size_t)(4 * bq + 1) * 512];
        u32 p2 = xp[(size_t)(4 * bq + 2) * 512];
        u32 p3 = xp[(size_t)(4 * bq + 3) * 512];
        float vx0 = __uint_as_float(p0 << 16);
        float vy0 = sgn * __uint_as_float(p0 & 0xffff0000u);
        float vx1 = __uint_as_float(p1 << 16);
        float vy1 = sgn * __uint_as_float(p1 & 0xffff0000u);
        float vx2 = __uint_as_float(p2 << 16);
        float vy2 = sgn * __uint_as_float(p2 & 0xffff0000u);
        float vx3 = __uint_as_float(p3 << 16);
        float vy3 = sgn * __uint_as_float(p3 & 0xffff0000u);
        const float4* wq = (const float4*)(wfT + (size_t)bq * (LTOT * 4));
#pragma unroll
        for (int j = 0; j < 4; j++) {
            if (lb + j >= l0) {
                float4 w = wq[tl[j]];
                acc[j].x += w.x * vx0 + w.y * vx1 + w.z * vx2 + w.w * vx3;
                acc[j].y += w.x * vy0 + w.y * vy1 + w.z * vy2 + w.w * vy3;
            }
        }
    }
    int s_i  = i >> 4;
    int kl   = 2 * (i & 15);
    int joff = kl & 7;
    int Lhi  = (kl >> 3) << 4;
#pragma unroll
    for (int j = 0; j < 4; j++) {
        int l = lb + j;
        if (l >= l0) {
            int mi = mh + l, ni = nh + l;
            int s   = 2 * ni + s_i;
            int row = 4 * mi + z;
            u32 pack = pack2bf(acc[j].x, acc[j].y);
            size_t off = (size_t)8192 * l * l + (size_t)s * 4096
                       + ((row >> 4) << 9) + ((Lhi + (row & 15)) << 3) + joff;
            *(u32*)(Ab + off) = pack;
        }
    }
}

// ---------------------------------------------------------------------------
// MFMA GEMM, R19: XCD-cohort swizzle + distance-4 register pipeline.
// Grid 1024 (all co-resident at 4 blocks/CU). Decode:
//   xcd = id&7, ord = id>>3, oq = ord&3, g = (ord>>2)*8 + xcd  (bijective)
//   g in [0,256) -> (l,n) by countdown over nl (sum nl = 256).
// The 4 oq-siblings of (l,n) + ~4 same-l groups share one XCD, adjacent
// launch slots -> the (l,step)-dependent A-panel (indep of n,oq!) is served
// from that XCD's L2 instead of L3 (was ~349MB L3 traffic, the 9TB/s wall).
// Two named buffer pairs refill 4 steps ahead. S = 4l+2: peel(2) + l x 4
// covers all steps exactly (NO tail -- R17 lesson). NO LDS, NO barriers;
// fragment-ordered yhb uint4 B loads; per-lane perm+xor; unconditional
// tail prefetch (OOB stays inside 60MB ws; values dead).
// Output zh_T[zo][t] float pairs, plain stores (single buffer; R15/R16:
// scattered-store reductions are poison).
// ---------------------------------------------------------------------------
__global__ __launch_bounds__(256) void k_gemm(const u16* __restrict__ Ab,
                                              const u32* __restrict__ yhb,
                                              float* __restrict__ zhT) {
    int id  = (int)blockIdx.x;
    int xcd = id & 7;
    int ord = id >> 3;            // [0,128) within XCD
    int oq  = ord & 3;
    int g   = ((ord >> 2) << 3) | xcd;   // group (l,n) in [0,256)
    int rem = g, l, nl = 1;
    for (l = 15; l >= 0; l--) {
        nl = 2 * l + 1;
        if (rem < nl) break;
        rem -= nl;
    }
    int n = rem;
    int base = LB[l];
    const u16* Ag = Ab + (size_t)8192 * l * l;
    int S = 2 * nl;

    int tid = threadIdx.x, lane = tid & 63, w = tid >> 6;
    int cc = lane & 1;
    u32 sel = cc ? 0x01000302u : 0x03020100u;   // ror16 : identity
    u32 msk = cc ? 0u          : 0x80000000u;   // 0     : negate-hi

    const u32* Bb = yhb + (size_t)(base + n) * 2048 + (oq << 8) + ((lane >> 1) << 2);
    const u16* Aw = Ag + ((w << 10) | (lane << 3));

    floatx4 acc[2][2];
#pragma unroll
    for (int a = 0; a < 2; a++)
#pragma unroll
        for (int b = 0; b < 2; b++) acc[a][b] = (floatx4)0.f;

#define LOADB(s, q0, q1) { \
    const uint4* bp = (const uint4*)(Bb + (size_t)((s) >> 1) * nl * 2048 + (((s) & 1) << 10)); \
    q0 = bp[0]; q1 = bp[32]; }
#define LOADA(s, r0, r1) { \
    const u16* apx = Aw + (size_t)(s) * 4096; \
    r0 = *(const short8*)apx; r1 = *(const short8*)(apx + 512); }
#define MF(a, b, c) __builtin_amdgcn_mfma_f32_16x16x32_bf16(a, b, c, 0, 0, 0)
// compute 2 steps from a pair's regs, then refill that pair from step snew
#define COMP2REFILL(Bx0, Bx1, Ax0, Ax1, By0, By1, Ay0, Ay1, snew) { \
    short8 bf0 = btr4(Bx0, sel, msk), bf1 = btr4(Bx1, sel, msk); \
    short8 af0 = Ax0, af1 = Ax1; \
    short8 cf0 = btr4(By0, sel, msk), cf1 = btr4(By1, sel, msk); \
    short8 ag0 = Ay0, ag1 = Ay1; \
    LOADA(snew, Ax0, Ax1); LOADB(snew, Bx0, Bx1); \
    LOADA((snew) + 1, Ay0, Ay1); LOADB((snew) + 1, By0, By1); \
    acc[0][0] = MF(af0, bf0, acc[0][0]);  acc[1][0] = MF(af1, bf0, acc[1][0]); \
    acc[0][1] = MF(af0, bf1, acc[0][1]);  acc[1][1] = MF(af1, bf1, acc[1][1]); \
    acc[0][0] = MF(ag0, cf0, acc[0][0]);  acc[1][0] = MF(ag1, cf0, acc[1][0]); \
    acc[0][1] = MF(ag0, cf1, acc[0][1]);  acc[1][1] = MF(ag1, cf1, acc[1][1]); }

    // pair0 = steps s, s+1; pair1 = steps s+2, s+3
    uint4 p0B0, p0B1, p0C0, p0C1; short8 p0a0, p0a1, p0c0, p0c1;
    uint4 p1B0, p1B1, p1C0, p1C1; short8 p1a0, p1a1, p1c0, p1c1;
    LOADA(0, p0a0, p0a1); LOADB(0, p0B0, p0B1);
    LOADA(1, p0c0, p0c1); LOADB(1, p0C0, p0C1);
    LOADA(2, p1a0, p1a1); LOADB(2, p1B0, p1B1);
    LOADA(3, p1c0, p1c1); LOADB(3, p1C0, p1C1);

    // peel: steps 0,1. Then l iterations of 4 steps = 4l -> total 4l+2 = S.
    COMP2REFILL(p0B0, p0B1, p0a0, p0a1, p0C0, p0C1, p0c0, p0c1, 4);
    for (int s = 2; s + 2 < S; s += 4) {
        COMP2REFILL(p1B0, p1B1, p1a0, p1a1, p1C0, p1C1, p1c0, p1c1, s + 4);
        COMP2REFILL(p0B0, p0B1, p0a0, p0a1, p0C0, p0C1, p0c0, p0c1, s + 6);
    }
    // no tail: loop covers through step S-1 (R17's tail was a double-count)
#undef COMP2REFILL
#undef LOADB
#undef LOADA
#undef MF

    int q = lane >> 4, cn = lane & 15;
#pragma unroll
    for (int mt = 0; mt < 2; mt++) {
#pragma unroll
        for (int nt = 0; nt < 2; nt++) {
            int nu2 = (nt << 4) + cn;
            int o2  = (oq << 4) + (nu2 >> 1);
            int c2  = nu2 & 1;
#pragma unroll
            for (int r = 0; r < 4; r++) {
                int R = (w << 5) + (mt << 4) + (q << 2) + r;
                int m = R >> 2, z = R & 3;
                if (m < nl) {
                    int t  = base + m * nl + n;
                    int zo = (z << 6) + o2;
                    zhT[((size_t)zo * LTOT + t) * 2 + c2] = acc[mt][nt][r];
                }
            }
        }
    }
}

// ---------------------------------------------------------------------------
// Inverse, 4 betas per block. R14: packed-fp32 complex math throughout.
// gather: v_pk_fma broadcast MACs; pass 1: register twiddle rotation chains,
// zero twiddle LDS; pass 2: 135->15 LDS ops/task via chains + symmetries.
// Grid: 2048 = (bq 8) x (zo 256); 256 thr; ~17.7KB LDS.
// ---------------------------------------------------------------------------
__global__ __launch_bounds__(256, 8) void k_inv2(const float2* __restrict__ zhT,
                                                 const float* __restrict__ wiT,
                                                 const float* __restrict__ bias,
                                                 float* __restrict__ out) {
    __shared__ __align__(16) f32x2 Pb[4 * 544];  // plane p at p*544, rows stride 34
    __shared__ f32x2 Wf[32];                     // (cos, sin) 2pi i/32
    int tid = threadIdx.x;
    int zo = blockIdx.x & 255;
    int bq = blockIdx.x >> 8;
    int b0 = bq * 4;
    if (tid < 32) {
        float sv, cv;
        sincosf(6.28318530717958647692f * (float)tid / 32.0f, &sv, &cv);
        f32x2 wv; wv.x = cv; wv.y = sv;
        Wf[tid] = wv;
    }
    // ---- gather: thread = (ng 32, rq 8); 2 ma-rows; 4 betas share each zv
    {
        int ng = tid & 31, rq = tid >> 5;
        int nh = (ng <= 15) ? ng : ng - 32;
        int an = nh < 0 ? -nh : nh;
        const f32x2* zr = (const f32x2*)zhT + (size_t)zo * LTOT;
        const f32x2* wp = (const f32x2*)wiT + (size_t)bq * (LTOT * 2);
#pragma unroll
        for (int mr = 0; mr < 2; mr++) {
            int ma = rq + 8 * mr;
            int l0 = ma > an ? ma : an;
            f32x2 a0 = (f32x2)0.f, a1 = a0, a2 = a0, a3 = a0;
#pragma unroll 4
            for (int l = 0; l < 16; l++) {
                if (l >= l0) {
                    int t = LB[l] + (ma + l) * (2 * l + 1) + (nh + l);
                    f32x2 zv = zr[t];
                    f32x2 w01 = wp[2 * t], w23 = wp[2 * t + 1];
                    a0 = fma_bl(w01, zv, a0);
                    a1 = fma_bh(w01, zv, a1);
                    a2 = fma_bl(w23, zv, a2);
                    a3 = fma_bh(w23, zv, a3);
                }
            }
            int po = ma * 34 + ng;
            Pb[po]            = a0;
            Pb[544 + po]      = a1;
            Pb[2 * 544 + po]  = a2;
            Pb[3 * 544 + po]  = a3;
        }
    }
    __syncthreads();
    // ---- pass 1 (ng -> g): 64 rows x 8 q = 512 tasks over 2 rounds.
#pragma unroll
    for (int it = 0; it < 2; it++) {
        int task = tid + it * 256;
        int rowid = task >> 3, q = task & 7;
        f32x2* prow = &Pb[(rowid >> 4) * 544 + (rowid & 15) * 34];
        const floatx4* prow4 = (const floatx4*)prow;
        floatx4 eo0 = prow4[0];
        f32x2 Ep; Ep.x = eo0.x; Ep.y = eo0.y;
        f32x2 Op; Op.x = eo0.z; Op.y = eo0.w;
        f32x2 En = (f32x2)0.f, On = (f32x2)0.f;
        f32x2 r = Wf[2 * q];
        f32x2 t = r;
#pragma unroll
        for (int h = 1; h < 16; h++) {
            floatx4 eo = prow4[h];
            f32x2 e; e.x = eo.x; e.y = eo.y;
            f32x2 o; o.x = eo.z; o.y = eo.w;
            if (h & 1) { En = cfma(e, t, En); On = cfma(o, t, On); }
            else       { Ep = cfma(e, t, Ep); Op = cfma(o, t, Op); }
            if (h < 15) t = cmulp(t, r);
        }
        f32x2 E0 = Ep + En, E1 = Ep - En;
        f32x2 O0 = Op + On, O1 = Op - On;
        f32x2 wq = Wf[q];
        f32x2 w0 = cmulp(O0, wq);
        f32x2 u1 = cmulp(O1, wq);
        f32x2 w1; w1.x = -u1.y; w1.y = u1.x;     // i * u1  (W^{q+8} = i W^q)
        prow[q]      = E0 + w0;
        prow[q + 16] = E0 - w0;
        prow[q + 8]  = E1 + w1;
        prow[q + 24] = E1 - w1;
    }
    __syncthreads();
    // ---- pass 2 (ma -> a): tasks (p, qa, g) x4 rounds; direct store + bias
    float bv = bias[zo & 63];
#pragma unroll
    for (int it = 0; it < 4; it++) {
        int task = tid + it * 256;
        int p = task >> 8, rr = task & 255;
        int qa = rr >> 5, g = rr & 31;
        const f32x2* pc = &Pb[p * 544];
        f32x2 r = Wf[2 * qa];
        f32x2 u = Wf[qa];
        f32x2 Uee = (f32x2)0.f, Ueo = Uee, Ve = Uee, Vo = Uee;
        f32x2 c0 = pc[g];
        {   // j = 0: odd column only
            f32x2 c1 = pc[34 + g];
            Ve = cfma(c1, u, Ve);
        }
        f32x2 t = r;
        u = cmulp(u, r);
#pragma unroll
        for (int j = 1; j < 8; j++) {
            f32x2 ce = pc[(2 * j) * 34 + g];
            f32x2 co = pc[(2 * j + 1) * 34 + g];
            if (j & 1) { Ueo = cfma(ce, t, Ueo); Vo = cfma(co, u, Vo); }
            else       { Uee = cfma(ce, t, Uee); Ve = cfma(co, u, Ve); }
            if (j < 7) { t = cmulp(t, r); u = cmulp(u, r); }
        }
        float EaA = c0.x + 2.f * (Uee.x + Ueo.x);
        float EaB = c0.x + 2.f * (Uee.x - Ueo.x);
        float OaA = 2.f * (Ve.x + Vo.x);
        float OaB = -2.f * (Ve.y - Vo.y);
        float* dst = out + (size_t)zo * 32768 + (size_t)(b0 + p) * 1024;
        constexpr float sc = 1.f / 1024.f;
        dst[qa * 32 + g]         = (EaA + OaA) * sc + bv;
        dst[(qa + 16) * 32 + g]  = (EaA - OaA) * sc + bv;
        dst[(qa + 8) * 32 + g]   = (EaB + OaB) * sc + bv;
        dst[(qa + 24) * 32 + g]  = (EaB - OaB) * sc + bv;
    }
}

// ---------------------------------------------------------------------------
extern "C" void kernel_launch(void* const* d_in, const int* in_sizes, int n_in,
                              void* d_out, int out_size, void* d_ws, size_t ws_size,
                              hipStream_t stream) {
    const float* x    = (const float*)d_in[0];
    const float* ker  = (const float*)d_in[1];
    const float* bias = (const float*)d_in[2];
    const float* wf   = (const float*)d_in[3];
    const float* wi   = (const float*)d_in[4];
    const float* Dre  = (const float*)d_in[5];
    const float* Dim  = (const float*)d_in[6];
    float* out = (float*)d_out;

    // layout: yhb 44.7MB | Ab 4.2MB | zh_T 11.2MB.
    // Xfb (8.4MB) + wfT (698KB, at zhT+8.39MB) alias zh_T: both dead once
    // k_gemm writes zhT. wiT (698KB) aliases yhb base: written after k_gemm
    // (yhb dead), read by k_inv2.
    char* ws = (char*)d_ws;
    u32*    yhb = (u32*)ws;
    u16*    Ab  = (u16*)(ws + 44695552);
    float*  zhT = (float*)(ws + 44695552 + 4194304);
    u32*    Xfb = (u32*)zhT;                                    // disjoint lifetime vs zh_T
    float*  wfT = (float*)(ws + 44695552 + 4194304 + 8388608);  // zhT tail, pre-gemm
    float*  wiT = (float*)ws;                                   // yhb region, post-gemm

    hipLaunchKernelGGL(k_fft_fwd, dim3(4096),  dim3(512), 0, stream, x, Xfb);
    hipLaunchKernelGGL(k_wtr,     dim3(22, 8), dim3(256), 0, stream, wf, wfT);
    hipLaunchKernelGGL(k_prep_B,  dim3(682),   dim3(256), 0, stream, Dre, Dim, ker, yhb);
    hipLaunchKernelGGL(k_beta_A,  dim3(2048),  dim3(256), 0, stream, Xfb, wfT, Ab);
    hipLaunchKernelGGL(k_gemm,    dim3(1024),  dim3(256), 0, stream, Ab, yhb, zhT);
    hipLaunchKernelGGL(k_wtr,     dim3(22, 8), dim3(256), 0, stream, wi, wiT);
    hipLaunchKernelGGL(k_inv2,    dim3(2048),  dim3(256), 0, stream,
                       (const float2*)zhT, wiT, bias, out);
}

// Round 12
// 202.047 us; speedup vs baseline: 1.0283x; 1.0283x over previous
//
#include <hip/hip_runtime.h>
#include <math.h>

// ---------------------------------------------------------------------------
// SO3 convolution. bf16 MFMA GEMM (complex-as-real); Hermitian-half FFT/IFFT.
// Pipeline: k_fft_fwd -> k_wtr(wf) -> k_prep_B -> k_beta_A
//           -> k_gemm (MFMA) -> k_wtr(wi) -> k_inv2
// R8 lesson: fusing fft+prep spilled -- keep kernels separate.
// R9: wfT/wiT [bq][t][4] transposes -- big win in k_beta_A.
// R10: k_inv2 streamed FFT passes (VGPR 92->64), 8 blocks/CU -- 68->~40us.
// R12: yhb in MFMA-fragment order; k_gemm no-LDS no-barrier -- ~49us.
// R13: o-quarter split, 1024 blocks -- Occ 13->27%, -12% time only.
// R14: k_inv2 packed-fp32 complex math + register twiddle chains -- <42us.
// R15 DISASTER: scattered atomics. R16 REGRESSION: two partial buffers =
// write-allocate RMW. Scattered-store reductions are poison in ANY form.
// R17 BROKEN (tail double-count). R18 = distance-4 pipeline: NEUTRAL ->
// k_gemm not latency-bound.
// R19 (-2%): A/L3-reuse cohort swizzle REFUTED the read theory but exposed
// the WRITE mechanism: zhT lines = 4 consecutive n (same l,oq). R19 split
// n-siblings across XCDs -> WRITE 25.6->47.5MB (4-way partial lines).
// R18's layout was 2-way (25.6MB for 11.2MB data).
// R20: INVERTED swizzle -- within each 32-id chunk, the 4 same-XCD ids
// (= mod 8) map to works at stride 4 = same (l,oq), n..n+3 = the 4 writers
// of each zhT line -> partials merge in one L2 -> full-line HBM writes,
// no write-allocate fetch. Quad also shares A-panel + B-rows in that L2.
// Workspace: yhb 44.7MB | Ab 4.2MB | zh_T 11.2MB.
//   Xfb (8.4MB) + wfT (698KB) alias zh_T (lifetime fft->gemm, disjoint).
//   wiT (698KB) aliases yhb base (written after gemm, read by inv2).
// ---------------------------------------------------------------------------

typedef unsigned short u16;
typedef unsigned int   u32;
typedef __attribute__((ext_vector_type(8))) short  short8;   // 8 bf16
typedef __attribute__((ext_vector_type(4))) float  floatx4;
typedef __attribute__((ext_vector_type(2))) float  f32x2;

constexpr int LTOT = 5456;

constexpr int LB[17] = {0,1,10,35,84,165,286,455,680,969,
                        1330,1771,2300,2925,3654,4495,5456};

__device__ inline u16 f2bf(float f) {
    u32 u = __float_as_uint(f);
    u += 0x7fff + ((u >> 16) & 1);
    return (u16)(u >> 16);
}
__device__ inline u32 pack2bf(float re, float im) {
    return (u32)f2bf(re) | ((u32)f2bf(im) << 16);
}

// cc-dependent complex pack transform: cc=0 -> (re,-im) == b ^ 0x80000000;
// cc=1 -> (im,re) == ror16(b). Done as per-lane-constant perm + xor.
__device__ inline short8 btr4(uint4 q, u32 sel, u32 msk) {
    uint4 t;
    t.x = __builtin_amdgcn_perm(q.x, q.x, sel) ^ msk;
    t.y = __builtin_amdgcn_perm(q.y, q.y, sel) ^ msk;
    t.z = __builtin_amdgcn_perm(q.z, q.z, sel) ^ msk;
    t.w = __builtin_amdgcn_perm(q.w, q.w, sel) ^ msk;
    return *(short8*)&t;
}

// ---- packed-fp32 complex helpers (VOP3P). acc/result = (re, im) pairs. ----
__device__ __forceinline__ f32x2 cfma(f32x2 e, f32x2 t, f32x2 acc) {
    asm("v_pk_fma_f32 %0, %1, %2, %0 op_sel:[0,0,0] op_sel_hi:[0,1,1]\n\t"
        "v_pk_fma_f32 %0, %1, %2, %0 op_sel:[1,1,0] op_sel_hi:[1,0,1] neg_lo:[0,1,0]"
        : "+v"(acc) : "v"(e), "v"(t));
    return acc;
}
__device__ __forceinline__ f32x2 cmulp(f32x2 t, f32x2 r) {
    f32x2 d;
    asm("v_pk_mul_f32 %0, %1, %2 op_sel:[0,0] op_sel_hi:[0,1]\n\t"
        "v_pk_fma_f32 %0, %1, %2, %0 op_sel:[1,1,0] op_sel_hi:[1,0,1] neg_lo:[0,1,0]"
        : "=&v"(d) : "v"(t), "v"(r));
    return d;
}
__device__ __forceinline__ f32x2 fma_bl(f32x2 w2, f32x2 v, f32x2 acc) {
    asm("v_pk_fma_f32 %0, %1, %2, %0 op_sel:[0,0,0] op_sel_hi:[0,1,1]"
        : "+v"(acc) : "v"(w2), "v"(v));
    return acc;
}
__device__ __forceinline__ f32x2 fma_bh(f32x2 w2, f32x2 v, f32x2 acc) {
    asm("v_pk_fma_f32 %0, %1, %2, %0 op_sel:[1,0,0] op_sel_hi:[1,1,1]"
        : "+v"(acc) : "v"(w2), "v"(v));
    return acc;
}

// ---------------------------------------------------------------------------
// Wigner-table transpose: w[32][LTOT] -> wT[bq(8)][t][4] so a 4-beta group is
// one float4. Grid (22, 8) x 256.
// ---------------------------------------------------------------------------
__global__ __launch_bounds__(256) void k_wtr(const float* __restrict__ w,
                                             float* __restrict__ wT) {
    int t  = blockIdx.x * 256 + threadIdx.x;
    int bq = blockIdx.y;
    if (t < LTOT) {
        float4 v;
        v.x = w[(size_t)(bq * 4 + 0) * LTOT + t];
        v.y = w[(size_t)(bq * 4 + 1) * LTOT + t];
        v.z = w[(size_t)(bq * 4 + 2) * LTOT + t];
        v.w = w[(size_t)(bq * 4 + 3) * LTOT + t];
        *(float4*)(wT + ((size_t)bq * LTOT + t) * 4) = v;
    }
}

// ---------------------------------------------------------------------------
// Forward FFT2 (e^{-i}), radix-2 both passes, 512 threads, one task each.
// Stores ONLY Hermitian-half rows ma 0..15, bf16-packed.
// x: [z][i][b][a][g].   Xfb: [zi*32+b][ma(0..15)][ng] packed bf16 pairs.
// ---------------------------------------------------------------------------
__global__ __launch_bounds__(512) void k_fft_fwd(const float* __restrict__ x,
                                                 u32* __restrict__ Xfb) {
    __shared__ float xs[1056];               // [a][g] stride 33
    __shared__ float Gre[1056], Gim[1056];   // [a][k] stride 33
    __shared__ float Wc[32], Ws[32];
    int tid = threadIdx.x;
    if (tid < 32) {
        float sv, cv;
        sincosf(6.28318530717958647692f * (float)tid / 32.0f, &sv, &cv);
        Wc[tid] = cv; Ws[tid] = sv;
    }
    const float* src = x + (size_t)blockIdx.x * 1024;
    for (int e = tid; e < 1024; e += 512) xs[(e >> 5) * 33 + (e & 31)] = src[e];
    __syncthreads();
    // pass 1 over g (real input), radix-2: task = (a, k in 0..15)
    {
        int a = tid >> 4, k = tid & 15;
        const float* row = &xs[a * 33];
        float Er = 0.f, Ei = 0.f, Or = 0.f, Oi = 0.f;
#pragma unroll
        for (int h = 0; h < 16; h++) {
            int idx = (2 * h * k) & 31;
            float c = Wc[idx], s = Ws[idx];
            float xe = row[2 * h], xo = row[2 * h + 1];
            Er += xe * c;  Ei -= xe * s;
            Or += xo * c;  Oi -= xo * s;
        }
        float WOr = Or * Wc[k] + Oi * Ws[k];
        float WOi = Oi * Wc[k] - Or * Ws[k];
        Gre[a * 33 + k]      = Er + WOr;
        Gim[a * 33 + k]      = Ei + WOi;
        Gre[a * 33 + k + 16] = Er - WOr;
        Gim[a * 33 + k + 16] = Ei - WOi;
    }
    __syncthreads();
    // pass 2 over a, radix-2 combine; store only row ma (0..15)
    {
        u32* dst = Xfb + (size_t)blockIdx.x * 512;
        int ng = tid & 31, ma = tid >> 5;
        float Er = 0.f, Ei = 0.f, Or = 0.f, Oi = 0.f;
#pragma unroll
        for (int h = 0; h < 16; h++) {
            int idx = (2 * h * ma) & 31;
            float c = Wc[idx], s = Ws[idx];
            float er = Gre[(2 * h) * 33 + ng],      ei = Gim[(2 * h) * 33 + ng];
            float orr = Gre[(2 * h + 1) * 33 + ng], oi = Gim[(2 * h + 1) * 33 + ng];
            Er += er * c + ei * s;   Ei += ei * c - er * s;
            Or += orr * c + oi * s;  Oi += oi * c - orr * s;
        }
        float WOr = Or * Wc[ma] + Oi * Ws[ma];
        float WOi = Oi * Wc[ma] - Or * Ws[ma];
        dst[ma * 32 + ng] = pack2bf(Er + WOr, Ei + WOi);
    }
}

// ---------------------------------------------------------------------------
// Build compact bf16 yh in MFMA-FRAGMENT ORDER (R12):
// io = (i,o): i = ih*16+kh*4+j, o = oh*32+nt*8+ph
// nio = ih*1024 + oh*512 + nt*128 + kh*32 + ph*4 + j
// so k_gemm's lane fragment (4 words j=0..3) is one contiguous uint4.
// ---------------------------------------------------------------------------
__global__ __launch_bounds__(256) void k_prep_B(const float* __restrict__ Dre,
                                                const float* __restrict__ Dim,
                                                const float* __restrict__ ker,
                                                u32* __restrict__ yhb) {
    __shared__ float Ds[8][24];
    int t0  = blockIdx.x * 8;
    int tid = threadIdx.x;
    if (tid < 192) {
        int rr = tid / 24, jj = tid - rr * 24;
        Ds[rr][jj] = (jj < 12) ? Dre[(t0 + rr) * 12 + jj] : Dim[(t0 + rr) * 12 + jj - 12];
    }
    __syncthreads();
    for (int rep = 0; rep < 8; rep++) {
        int io = rep * 256 + tid;
        int i  = io >> 6, o = io & 63;
        int nio = ((i >> 4) << 10) + ((o >> 5) << 9) + (((o >> 3) & 3) << 7)
                + (((i >> 2) & 3) << 5) + ((o & 7) << 2) + (i & 3);
        const float4* kp = (const float4*)(ker + io * 12);
        float4 ka = kp[0], kb = kp[1], kc = kp[2];
        float kv[12] = {ka.x, ka.y, ka.z, ka.w, kb.x, kb.y, kb.z, kb.w,
                        kc.x, kc.y, kc.z, kc.w};
#pragma unroll
        for (int rr = 0; rr < 8; rr++) {
            float sr = 0.f, si = 0.f;
#pragma unroll
            for (int j = 0; j < 12; j++) {
                sr += Ds[rr][j]      * kv[j];
                si += Ds[rr][12 + j] * kv[j];
            }
            yhb[(size_t)(t0 + rr) * 2048 + nio] = pack2bf(sr, si);
        }
    }
}

// ---------------------------------------------------------------------------
// Fused beta-contraction + bf16 A-fragment pack. Xfb is Hermitian-half:
// rows ma 0..15 stored; ma>=17 read as conj(Xf[32-ma][(32-ng)&31]).
// Grid: (ma 32) x (zig 64) = 2048 blocks; thread = (zil 2, lq 4, ng 32).
// R9: b-loop grouped in beta-quads; wfT[bq][t][4] gives one float4 per
// (bq, l) instead of 4 scalar strided loads.
// ---------------------------------------------------------------------------
__global__ __launch_bounds__(256) void k_beta_A(const u32* __restrict__ Xfb,
                                                const float* __restrict__ wfT,
                                                u16* __restrict__ Ab) {
    int ma  = blockIdx.x >> 6;
    int zig = blockIdx.x & 63;
    int tid = threadIdx.x;
    int ng  = tid & 31;
    int lq  = (tid >> 5) & 3;
    int zil = tid >> 7;
    int zi  = zig * 2 + zil;
    int z = zi >> 5, i = zi & 31;
    int mh = (ma <= 15) ? ma : ma - 32;
    int nh = (ng <= 15) ? ng : ng - 32;
    int am = mh < 0 ? -mh : mh;
    int an = nh < 0 ? -nh : nh;
    int l0 = am > an ? am : an;
    int lb = lq * 4;

    int isconj = (ma > 16);
    int mau = isconj ? (32 - ma) : ma;
    int ngu = isconj ? ((32 - ng) & 31) : ng;
    if (mau > 15) { mau = 0; ngu = 0; }   // ma==16: l0==16, values unused

    int tl[4];
#pragma unroll
    for (int j = 0; j < 4; j++) {
        int l = lb + j;
        tl[j] = LB[l] + (mh + l) * (2 * l + 1) + (nh + l);
    }
    float2 acc[4];
#pragma unroll
    for (int j = 0; j < 4; j++) acc[j] = make_float2(0.f, 0.f);

    const u32* xp = Xfb + (size_t)zi * 32 * 512 + mau * 32 + ngu;
    float sgn = isconj ? -1.f : 1.f;
#pragma unroll 2
    for (int bq = 0; bq < 8; bq++) {
        u32 p0 = xp[(size_t)(4 * bq + 0) * 512];
        u32 p1 = xp[(size_t)(4 * bq + 1) * 512];
        u32 p2 = xp[(size_t)(4 * bq + 2) * 512];
        u32 p3 = xp[(size_t)(4 * bq + 3) * 512];
        float vx0 = __uint_as_float(p0 << 16);
        float vy0 = sgn * __uint_as_float(p0 & 0xffff0000u);
        float vx1 = __uint_as_float(p1 << 16);
        float vy1 = sgn * __uint_as_float(p1 & 0xffff0000u);
        float vx2 = __uint_as_float(p2 << 16);
        float vy2 = sgn * __uint_as_float(p2 & 0xffff0000u);
        float vx3 = __uint_as_float(p3 << 16);
        float vy3 = sgn * __uint_as_float(p3 & 0xffff0000u);
        const float4* wq = (const float4*)(wfT + (size_t)bq * (LTOT * 4));
#pragma unroll
        for (int j = 0; j < 4; j++) {
            if (lb + j >= l0) {
                float4 w = wq[tl[j]];
                acc[j].x += w.x * vx0 + w.y * vx1 + w.z * vx2 + w.w * vx3;
                acc[j].y += w.x * vy0 + w.y * vy1 + w.z * vy2 + w.w * vy3;
            }
        }
    }
    int s_i  = i >> 4;
    int kl   = 2 * (i & 15);
    int joff = kl & 7;
    int Lhi  = (kl >> 3) << 4;
#pragma unroll
    for (int j = 0; j < 4; j++) {
        int l = lb + j;
        if (l >= l0) {
            int mi = mh + l, ni = nh + l;
            int s   = 2 * ni + s_i;
            int row = 4 * mi + z;
            u32 pack = pack2bf(acc[j].x, acc[j].y);
            size_t off = (size_t)8192 * l * l + (size_t)s * 4096
                       + ((row >> 4) << 9) + ((Lhi + (row & 15)) << 3) + joff;
            *(u32*)(Ab + off) = pack;
        }
    }
}

// ---------------------------------------------------------------------------
// MFMA GEMM, R20: line-writer XCD grouping + distance-4 register pipeline.
// Grid 1024 (all co-resident, 4 blocks/CU). Within each aligned 32-id chunk:
//   o = id&31, g = o&7, k5 = o>>3;  work = (id&~31) | (g&3) | ((g>>2)<<4) | (k5<<2)
// Bijective; the 4 ids with equal g (differ by 8 -> SAME XCD) map to works
// at stride 4 = same (l, oq), n..n+3 = the 4 writers of each 64B zhT line.
// Their partial stores merge in one XCD's L2 -> full-line HBM writes (R18
// was 2-way-split: 25.6MB written for 11.2MB data; R19 4-way: 47.5MB).
// Quad also shares its A-panel and B-rows in that L2.
// Work decode (big-l first) unchanged: countdown over 4nl; n=rem>>2, oq=rem&3.
// Two named buffer pairs refill 4 steps ahead. S = 4l+2: peel(2) + l x 4
// covers all steps exactly (NO tail -- R17 lesson). NO LDS, NO barriers;
// fragment-ordered yhb uint4 B loads; per-lane perm+xor; unconditional
// tail prefetch (OOB stays inside 60MB ws; values dead).
// Output zh_T[zo][t] float pairs, plain stores (single buffer; R15/R16:
// scattered-store reductions are poison).
// ---------------------------------------------------------------------------
__global__ __launch_bounds__(256) void k_gemm(const u16* __restrict__ Ab,
                                              const u32* __restrict__ yhb,
                                              float* __restrict__ zhT) {
    int id  = (int)blockIdx.x;
    int o5  = id & 31;
    int g   = o5 & 7;
    int k5  = o5 >> 3;
    int flat = (id & ~31) | ((g & 3) + ((g >> 2) << 4) + (k5 << 2));
    int rem = flat, l, nl = 1;
    for (l = 15; l >= 0; l--) {
        nl = 2 * l + 1;
        int c = nl * 4;
        if (rem < c) break;
        rem -= c;
    }
    int n  = rem >> 2;
    int oq = rem & 3;
    int base = LB[l];
    const u16* Ag = Ab + (size_t)8192 * l * l;
    int S = 2 * nl;

    int tid = threadIdx.x, lane = tid & 63, w = tid >> 6;
    int cc = lane & 1;
    u32 sel = cc ? 0x01000302u : 0x03020100u;   // ror16 : identity
    u32 msk = cc ? 0u          : 0x80000000u;   // 0     : negate-hi

    const u32* Bb = yhb + (size_t)(base + n) * 2048 + (oq << 8) + ((lane >> 1) << 2);
    const u16* Aw = Ag + ((w << 10) | (lane << 3));

    floatx4 acc[2][2];
#pragma unroll
    for (int a = 0; a < 2; a++)
#pragma unroll
        for (int b = 0; b < 2; b++) acc[a][b] = (floatx4)0.f;

#define LOADB(s, q0, q1) { \
    const uint4* bp = (const uint4*)(Bb + (size_t)((s) >> 1) * nl * 2048 + (((s) & 1) << 10)); \
    q0 = bp[0]; q1 = bp[32]; }
#define LOADA(s, r0, r1) { \
    const u16* apx = Aw + (size_t)(s) * 4096; \
    r0 = *(const short8*)apx; r1 = *(const short8*)(apx + 512); }
#define MF(a, b, c) __builtin_amdgcn_mfma_f32_16x16x32_bf16(a, b, c, 0, 0, 0)
// compute 2 steps from a pair's regs, then refill that pair from step snew
#define COMP2REFILL(Bx0, Bx1, Ax0, Ax1, By0, By1, Ay0, Ay1, snew) { \
    short8 bf0 = btr4(Bx0, sel, msk), bf1 = btr4(Bx1, sel, msk); \
    short8 af0 = Ax0, af1 = Ax1; \
    short8 cf0 = btr4(By0, sel, msk), cf1 = btr4(By1, sel, msk); \
    short8 ag0 = Ay0, ag1 = Ay1; \
    LOADA(snew, Ax0, Ax1); LOADB(snew, Bx0, Bx1); \
    LOADA((snew) + 1, Ay0, Ay1); LOADB((snew) + 1, By0, By1); \
    acc[0][0] = MF(af0, bf0, acc[0][0]);  acc[1][0] = MF(af1, bf0, acc[1][0]); \
    acc[0][1] = MF(af0, bf1, acc[0][1]);  acc[1][1] = MF(af1, bf1, acc[1][1]); \
    acc[0][0] = MF(ag0, cf0, acc[0][0]);  acc[1][0] = MF(ag1, cf0, acc[1][0]); \
    acc[0][1] = MF(ag0, cf1, acc[0][1]);  acc[1][1] = MF(ag1, cf1, acc[1][1]); }

    // pair0 = steps s, s+1; pair1 = steps s+2, s+3
    uint4 p0B0, p0B1, p0C0, p0C1; short8 p0a0, p0a1, p0c0, p0c1;
    uint4 p1B0, p1B1, p1C0, p1C1; short8 p1a0, p1a1, p1c0, p1c1;
    LOADA(0, p0a0, p0a1); LOADB(0, p0B0, p0B1);
    LOADA(1, p0c0, p0c1); LOADB(1, p0C0, p0C1);
    LOADA(2, p1a0, p1a1); LOADB(2, p1B0, p1B1);
    LOADA(3, p1c0, p1c1); LOADB(3, p1C0, p1C1);

    // peel: steps 0,1. Then l iterations of 4 steps = 4l -> total 4l+2 = S.
    COMP2REFILL(p0B0, p0B1, p0a0, p0a1, p0C0, p0C1, p0c0, p0c1, 4);
    for (int s = 2; s + 2 < S; s += 4) {
        COMP2REFILL(p1B0, p1B1, p1a0, p1a1, p1C0, p1C1, p1c0, p1c1, s + 4);
        COMP2REFILL(p0B0, p0B1, p0a0, p0a1, p0C0, p0C1, p0c0, p0c1, s + 6);
    }
    // no tail: loop covers through step S-1 (R17's tail was a double-count)
#undef COMP2REFILL
#undef LOADB
#undef LOADA
#undef MF

    int q = lane >> 4, cn = lane & 15;
#pragma unroll
    for (int mt = 0; mt < 2; mt++) {
#pragma unroll
        for (int nt = 0; nt < 2; nt++) {
            int nu2 = (nt << 4) + cn;
            int o2  = (oq << 4) + (nu2 >> 1);
            int c2  = nu2 & 1;
#pragma unroll
            for (int r = 0; r < 4; r++) {
                int R = (w << 5) + (mt << 4) + (q << 2) + r;
                int m = R >> 2, z = R & 3;
                if (m < nl) {
                    int t  = base + m * nl + n;
                    int zo = (z << 6) + o2;
                    zhT[((size_t)zo * LTOT + t) * 2 + c2] = acc[mt][nt][r];
                }
            }
        }
    }
}

// ---------------------------------------------------------------------------
// Inverse, 4 betas per block. R14: packed-fp32 complex math throughout.
// gather: v_pk_fma broadcast MACs; pass 1: register twiddle rotation chains,
// zero twiddle LDS; pass 2: 135->15 LDS ops/task via chains + symmetries.
// Grid: 2048 = (bq 8) x (zo 256); 256 thr; ~17.7KB LDS.
// ---------------------------------------------------------------------------
__global__ __launch_bounds__(256, 8) void k_inv2(const float2* __restrict__ zhT,
                                                 const float* __restrict__ wiT,
                                                 const float* __restrict__ bias,
                                                 float* __restrict__ out) {
    __shared__ __align__(16) f32x2 Pb[4 * 544];  // plane p at p*544, rows stride 34
    __shared__ f32x2 Wf[32];                     // (cos, sin) 2pi i/32
    int tid = threadIdx.x;
    int zo = blockIdx.x & 255;
    int bq = blockIdx.x >> 8;
    int b0 = bq * 4;
    if (tid < 32) {
        float sv, cv;
        sincosf(6.28318530717958647692f * (float)tid / 32.0f, &sv, &cv);
        f32x2 wv; wv.x = cv; wv.y = sv;
        Wf[tid] = wv;
    }
    // ---- gather: thread = (ng 32, rq 8); 2 ma-rows; 4 betas share each zv
    {
        int ng = tid & 31, rq = tid >> 5;
        int nh = (ng <= 15) ? ng : ng - 32;
        int an = nh < 0 ? -nh : nh;
        const f32x2* zr = (const f32x2*)zhT + (size_t)zo * LTOT;
        const f32x2* wp = (const f32x2*)wiT + (size_t)bq * (LTOT * 2);
#pragma unroll
        for (int mr = 0; mr < 2; mr++) {
            int ma = rq + 8 * mr;
            int l0 = ma > an ? ma : an;
            f32x2 a0 = (f32x2)0.f, a1 = a0, a2 = a0, a3 = a0;
#pragma unroll 4
            for (int l = 0; l < 16; l++) {
                if (l >= l0) {
                    int t = LB[l] + (ma + l) * (2 * l + 1) + (nh + l);
                    f32x2 zv = zr[t];
                    f32x2 w01 = wp[2 * t], w23 = wp[2 * t + 1];
                    a0 = fma_bl(w01, zv, a0);
                    a1 = fma_bh(w01, zv, a1);
                    a2 = fma_bl(w23, zv, a2);
                    a3 = fma_bh(w23, zv, a3);
                }
            }
            int po = ma * 34 + ng;
            Pb[po]            = a0;
            Pb[544 + po]      = a1;
            Pb[2 * 544 + po]  = a2;
            Pb[3 * 544 + po]  = a3;
        }
    }
    __syncthreads();
    // ---- pass 1 (ng -> g): 64 rows x 8 q = 512 tasks over 2 rounds.
#pragma unroll
    for (int it = 0; it < 2; it++) {
        int task = tid + it * 256;
        int rowid = task >> 3, q = task & 7;
        f32x2* prow = &Pb[(rowid >> 4) * 544 + (rowid & 15) * 34];
        const floatx4* prow4 = (const floatx4*)prow;
        floatx4 eo0 = prow4[0];
        f32x2 Ep; Ep.x = eo0.x; Ep.y = eo0.y;
        f32x2 Op; Op.x = eo0.z; Op.y = eo0.w;
        f32x2 En = (f32x2)0.f, On = (f32x2)0.f;
        f32x2 r = Wf[2 * q];
        f32x2 t = r;
#pragma unroll
        for (int h = 1; h < 16; h++) {
            floatx4 eo = prow4[h];
            f32x2 e; e.x = eo.x; e.y = eo.y;
            f32x2 o; o.x = eo.z; o.y = eo.w;
            if (h & 1) { En = cfma(e, t, En); On = cfma(o, t, On); }
            else       { Ep = cfma(e, t, Ep); Op = cfma(o, t, Op); }
            if (h < 15) t = cmulp(t, r);
        }
        f32x2 E0 = Ep + En, E1 = Ep - En;
        f32x2 O0 = Op + On, O1 = Op - On;
        f32x2 wq = Wf[q];
        f32x2 w0 = cmulp(O0, wq);
        f32x2 u1 = cmulp(O1, wq);
        f32x2 w1; w1.x = -u1.y; w1.y = u1.x;     // i * u1  (W^{q+8} = i W^q)
        prow[q]      = E0 + w0;
        prow[q + 16] = E0 - w0;
        prow[q + 8]  = E1 + w1;
        prow[q + 24] = E1 - w1;
    }
    __syncthreads();
    // ---- pass 2 (ma -> a): tasks (p, qa, g) x4 rounds; direct store + bias
    float bv = bias[zo & 63];
#pragma unroll
    for (int it = 0; it < 4; it++) {
        int task = tid + it * 256;
        int p = task >> 8, rr = task & 255;
        int qa = rr >> 5, g = rr & 31;
        const f32x2* pc = &Pb[p * 544];
        f32x2 r = Wf[2 * qa];
        f32x2 u = Wf[qa];
        f32x2 Uee = (f32x2)0.f, Ueo = Uee, Ve = Uee, Vo = Uee;
        f32x2 c0 = pc[g];
        {   // j = 0: odd column only
            f32x2 c1 = pc[34 + g];
            Ve = cfma(c1, u, Ve);
        }
        f32x2 t = r;
        u = cmulp(u, r);
#pragma unroll
        for (int j = 1; j < 8; j++) {
            f32x2 ce = pc[(2 * j) * 34 + g];
            f32x2 co = pc[(2 * j + 1) * 34 + g];
            if (j & 1) { Ueo = cfma(ce, t, Ueo); Vo = cfma(co, u, Vo); }
            else       { Uee = cfma(ce, t, Uee); Ve = cfma(co, u, Ve); }
            if (j < 7) { t = cmulp(t, r); u = cmulp(u, r); }
        }
        float EaA = c0.x + 2.f * (Uee.x + Ueo.x);
        float EaB = c0.x + 2.f * (Uee.x - Ueo.x);
        float OaA = 2.f * (Ve.x + Vo.x);
        float OaB = -2.f * (Ve.y - Vo.y);
        float* dst = out + (size_t)zo * 32768 + (size_t)(b0 + p) * 1024;
        constexpr float sc = 1.f / 1024.f;
        dst[qa * 32 + g]         = (EaA + OaA) * sc + bv;
        dst[(qa + 16) * 32 + g]  = (EaA - OaA) * sc + bv;
        dst[(qa + 8) * 32 + g]   = (EaB + OaB) * sc + bv;
        dst[(qa + 24) * 32 + g]  = (EaB - OaB) * sc + bv;
    }
}

// ---------------------------------------------------------------------------
extern "C" void kernel_launch(void* const* d_in, const int* in_sizes, int n_in,
                              void* d_out, int out_size, void* d_ws, size_t ws_size,
                              hipStream_t stream) {
    const float* x    = (const float*)d_in[0];
    const float* ker  = (const float*)d_in[1];
    const float* bias = (const float*)d_in[2];
    const float* wf   = (const float*)d_in[3];
    const float* wi   = (const float*)d_in[4];
    const float* Dre  = (const float*)d_in[5];
    const float* Dim  = (const float*)d_in[6];
    float* out = (float*)d_out;

    // layout: yhb 44.7MB | Ab 4.2MB | zh_T 11.2MB.
    // Xfb (8.4MB) + wfT (698KB, at zhT+8.39MB) alias zh_T: both dead once
    // k_gemm writes zhT. wiT (698KB) aliases yhb base: written after k_gemm
    // (yhb dead), read by k_inv2.
    char* ws = (char*)d_ws;
    u32*    yhb = (u32*)ws;
    u16*    Ab  = (u16*)(ws + 44695552);
    float*  zhT = (float*)(ws + 44695552 + 4194304);
    u32*    Xfb = (u32*)zhT;                                    // disjoint lifetime vs zh_T
    float*  wfT = (float*)(ws + 44695552 + 4194304 + 8388608);  // zhT tail, pre-gemm
    float*  wiT = (float*)ws;                                   // yhb region, post-gemm

    hipLaunchKernelGGL(k_fft_fwd, dim3(4096),  dim3(512), 0, stream, x, Xfb);
    hipLaunchKernelGGL(k_wtr,     dim3(22, 8), dim3(256), 0, stream, wf, wfT);
    hipLaunchKernelGGL(k_prep_B,  dim3(682),   dim3(256), 0, stream, Dre, Dim, ker, yhb);
    hipLaunchKernelGGL(k_beta_A,  dim3(2048),  dim3(256), 0, stream, Xfb, wfT, Ab);
    hipLaunchKernelGGL(k_gemm,    dim3(1024),  dim3(256), 0, stream, Ab, yhb, zhT);
    hipLaunchKernelGGL(k_wtr,     dim3(22, 8), dim3(256), 0, stream, wi, wiT);
    hipLaunchKernelGGL(k_inv2,    dim3(2048),  dim3(256), 0, stream,
                       (const float2*)zhT, wiT, bias, out);
}

// Round 13
// 200.691 us; speedup vs baseline: 1.0352x; 1.0068x over previous
//
#include <hip/hip_runtime.h>
#include <math.h>

// ---------------------------------------------------------------------------
// SO3 convolution. bf16 MFMA GEMM (complex-as-real); Hermitian-half FFT/IFFT.
// Pipeline: k_fft_fwd -> k_wtr(wf) -> k_prep_B -> k_beta_A
//           -> k_gemm (MFMA) -> k_wtr(wi) -> k_inv2
// R8 lesson: fusing fft+prep spilled -- keep kernels separate.
// R9: wfT/wiT [bq][t][4] transposes -- big win in k_beta_A.
// R10: k_inv2 streamed FFT passes (VGPR 92->64), 8 blocks/CU -- 68->~40us.
// R12: yhb in MFMA-fragment order; k_gemm no-LDS no-barrier -- ~49us.
// R13: o-quarter split, 1024 blocks. R14: k_inv2 packed-fp32 + register
// twiddle chains -- ~28us. R15/R16: scattered-store reductions are poison
// in ANY form (atomics = 155us, split buffers = 70us).
// R17 BROKEN (tail double-count). R18 distance-4 pipeline: NEUTRAL.
// R19/R20 placement swizzles: neutral (R20 kept: groups the 4 zhT-line
// writers per XCD). k_gemm floor ~41us, k_inv2 ~28: both below the 42us
// harness-fill visibility threshold now.
// R21: front half (~125us: fft_fwd+prep_B+beta_A+2wtr, never profiled) is
// the largest remaining mass. (a) k_fft_fwd: packed-complex rewrite (R14
// recipe): v_pk_fma cmacs + register twiddle chains, conjugated table,
// float2 LDS rows -- VALU+LDS ops ~halved. (b) k_prep_B: 2 rows/block,
// grid 682->2728 (2.7->10.7 waves/SIMD).
// Workspace: yhb 44.7MB | Ab 4.2MB | zh_T 11.2MB.
//   Xfb (8.4MB) + wfT (698KB) alias zh_T (lifetime fft->gemm, disjoint).
//   wiT (698KB) aliases yhb base (written after gemm, read by inv2).
// ---------------------------------------------------------------------------

typedef unsigned short u16;
typedef unsigned int   u32;
typedef __attribute__((ext_vector_type(8))) short  short8;   // 8 bf16
typedef __attribute__((ext_vector_type(4))) float  floatx4;
typedef __attribute__((ext_vector_type(2))) float  f32x2;

constexpr int LTOT = 5456;

constexpr int LB[17] = {0,1,10,35,84,165,286,455,680,969,
                        1330,1771,2300,2925,3654,4495,5456};

__device__ inline u16 f2bf(float f) {
    u32 u = __float_as_uint(f);
    u += 0x7fff + ((u >> 16) & 1);
    return (u16)(u >> 16);
}
__device__ inline u32 pack2bf(float re, float im) {
    return (u32)f2bf(re) | ((u32)f2bf(im) << 16);
}

// cc-dependent complex pack transform: cc=0 -> (re,-im) == b ^ 0x80000000;
// cc=1 -> (im,re) == ror16(b). Done as per-lane-constant perm + xor.
__device__ inline short8 btr4(uint4 q, u32 sel, u32 msk) {
    uint4 t;
    t.x = __builtin_amdgcn_perm(q.x, q.x, sel) ^ msk;
    t.y = __builtin_amdgcn_perm(q.y, q.y, sel) ^ msk;
    t.z = __builtin_amdgcn_perm(q.z, q.z, sel) ^ msk;
    t.w = __builtin_amdgcn_perm(q.w, q.w, sel) ^ msk;
    return *(short8*)&t;
}

// ---- packed-fp32 complex helpers (VOP3P). acc/result = (re, im) pairs. ----
__device__ __forceinline__ f32x2 cfma(f32x2 e, f32x2 t, f32x2 acc) {
    asm("v_pk_fma_f32 %0, %1, %2, %0 op_sel:[0,0,0] op_sel_hi:[0,1,1]\n\t"
        "v_pk_fma_f32 %0, %1, %2, %0 op_sel:[1,1,0] op_sel_hi:[1,0,1] neg_lo:[0,1,0]"
        : "+v"(acc) : "v"(e), "v"(t));
    return acc;
}
__device__ __forceinline__ f32x2 cmulp(f32x2 t, f32x2 r) {
    f32x2 d;
    asm("v_pk_mul_f32 %0, %1, %2 op_sel:[0,0] op_sel_hi:[0,1]\n\t"
        "v_pk_fma_f32 %0, %1, %2, %0 op_sel:[1,1,0] op_sel_hi:[1,0,1] neg_lo:[0,1,0]"
        : "=&v"(d) : "v"(t), "v"(r));
    return d;
}
__device__ __forceinline__ f32x2 fma_bl(f32x2 w2, f32x2 v, f32x2 acc) {
    asm("v_pk_fma_f32 %0, %1, %2, %0 op_sel:[0,0,0] op_sel_hi:[0,1,1]"
        : "+v"(acc) : "v"(w2), "v"(v));
    return acc;
}
__device__ __forceinline__ f32x2 fma_bh(f32x2 w2, f32x2 v, f32x2 acc) {
    asm("v_pk_fma_f32 %0, %1, %2, %0 op_sel:[1,0,0] op_sel_hi:[1,1,1]"
        : "+v"(acc) : "v"(w2), "v"(v));
    return acc;
}

// ---------------------------------------------------------------------------
// Wigner-table transpose: w[32][LTOT] -> wT[bq(8)][t][4] so a 4-beta group is
// one float4. Grid (22, 8) x 256.
// ---------------------------------------------------------------------------
__global__ __launch_bounds__(256) void k_wtr(const float* __restrict__ w,
                                             float* __restrict__ wT) {
    int t  = blockIdx.x * 256 + threadIdx.x;
    int bq = blockIdx.y;
    if (t < LTOT) {
        float4 v;
        v.x = w[(size_t)(bq * 4 + 0) * LTOT + t];
        v.y = w[(size_t)(bq * 4 + 1) * LTOT + t];
        v.z = w[(size_t)(bq * 4 + 2) * LTOT + t];
        v.w = w[(size_t)(bq * 4 + 3) * LTOT + t];
        *(float4*)(wT + ((size_t)bq * LTOT + t) * 4) = v;
    }
}

// ---------------------------------------------------------------------------
// Forward FFT2 (e^{-i}), R21: packed-complex (R14 recipe). 512 threads.
// pass 1 (g-DFT, real input): task (a, k 0..15); per h: ONE ds_read_b64
// (xe,xo adjacent; xs stride 34 for 8B align) + 2 broadcast pk-FMA +
// register twiddle chain t *= conj(W^{2k}) -- no LDS twiddle reads.
// pass 2 (a-DFT): complex rows Gc (float2, stride 33); per h: 2 b64 reads
// + 2 cfma + chain. Stores ONLY Hermitian-half rows ma 0..15, bf16-packed.
// x: [z][i][b][a][g].   Xfb: [zi*32+b][ma(0..15)][ng] packed bf16 pairs.
// ---------------------------------------------------------------------------
__global__ __launch_bounds__(512) void k_fft_fwd(const float* __restrict__ x,
                                                 u32* __restrict__ Xfb) {
    __shared__ __align__(8) float xs[1088];    // [a][g] stride 34 (8B-aligned rows)
    __shared__ __align__(8) f32x2 Gc[1056];    // [a][k] stride 33, (re,im)
    __shared__ f32x2 Wfc[32];                  // (cos, -sin): conj table
    int tid = threadIdx.x;
    if (tid < 32) {
        float sv, cv;
        sincosf(6.28318530717958647692f * (float)tid / 32.0f, &sv, &cv);
        f32x2 wv; wv.x = cv; wv.y = -sv;
        Wfc[tid] = wv;
    }
    const float* src = x + (size_t)blockIdx.x * 1024;
    for (int e = tid; e < 1024; e += 512) xs[(e >> 5) * 34 + (e & 31)] = src[e];
    __syncthreads();
    // pass 1: E += xe*conj(W)^{2hk}, O += xo*conj(W)^{2hk}; out k, k+16
    {
        int a = tid >> 4, k = tid & 15;
        const f32x2* rowp = (const f32x2*)&xs[a * 34];
        f32x2 r = Wfc[2 * k];
        f32x2 p0 = rowp[0];
        f32x2 E; E.x = p0.x; E.y = 0.f;
        f32x2 O; O.x = p0.y; O.y = 0.f;
        f32x2 t = r;
#pragma unroll
        for (int h = 1; h < 16; h++) {
            f32x2 p = rowp[h];               // (xe, xo)
            E = fma_bl(p, t, E);             // E += xe * t
            O = fma_bh(p, t, O);             // O += xo * t
            if (h < 15) t = cmulp(t, r);
        }
        f32x2 WO = cmulp(O, Wfc[k]);         // O * conj(W^k)
        Gc[a * 33 + k]      = E + WO;
        Gc[a * 33 + k + 16] = E - WO;
    }
    __syncthreads();
    // pass 2: E += e*conj(W)^{2h*ma}; store row ma (0..15)
    {
        u32* dst = Xfb + (size_t)blockIdx.x * 512;
        int ng = tid & 31, ma = tid >> 5;
        f32x2 r = Wfc[2 * ma];
        f32x2 E = Gc[ng];                    // a = 0
        f32x2 O = Gc[33 + ng];               // a = 1
        f32x2 t = r;
#pragma unroll
        for (int h = 1; h < 16; h++) {
            f32x2 e = Gc[(2 * h) * 33 + ng];
            f32x2 o = Gc[(2 * h + 1) * 33 + ng];
            E = cfma(e, t, E);
            O = cfma(o, t, O);
            if (h < 15) t = cmulp(t, r);
        }
        f32x2 WO = cmulp(O, Wfc[ma]);
        dst[ma * 32 + ng] = pack2bf(E.x + WO.x, E.y + WO.y);
    }
}

// ---------------------------------------------------------------------------
// Build compact bf16 yh in MFMA-FRAGMENT ORDER (R12):
// io = (i,o): i = ih*16+kh*4+j, o = oh*32+nt*8+ph
// nio = ih*1024 + oh*512 + nt*128 + kh*32 + ph*4 + j
// R21: 2 t-rows per block (was 8), grid 682 -> 2728: 2.7 -> 10.7 waves/SIMD
// to hide ker-load/yhb-store latency. Total FMA conserved; ker (98KB) L2-hot.
// ---------------------------------------------------------------------------
__global__ __launch_bounds__(256) void k_prep_B(const float* __restrict__ Dre,
                                                const float* __restrict__ Dim,
                                                const float* __restrict__ ker,
                                                u32* __restrict__ yhb) {
    __shared__ float Ds[2][24];
    int t0  = blockIdx.x * 2;
    int tid = threadIdx.x;
    if (tid < 48) {
        int rr = tid / 24, jj = tid - rr * 24;
        Ds[rr][jj] = (jj < 12) ? Dre[(t0 + rr) * 12 + jj] : Dim[(t0 + rr) * 12 + jj - 12];
    }
    __syncthreads();
    for (int rep = 0; rep < 8; rep++) {
        int io = rep * 256 + tid;
        int i  = io >> 6, o = io & 63;
        int nio = ((i >> 4) << 10) + ((o >> 5) << 9) + (((o >> 3) & 3) << 7)
                + (((i >> 2) & 3) << 5) + ((o & 7) << 2) + (i & 3);
        const float4* kp = (const float4*)(ker + io * 12);
        float4 ka = kp[0], kb = kp[1], kc = kp[2];
        float kv[12] = {ka.x, ka.y, ka.z, ka.w, kb.x, kb.y, kb.z, kb.w,
                        kc.x, kc.y, kc.z, kc.w};
#pragma unroll
        for (int rr = 0; rr < 2; rr++) {
            float sr = 0.f, si = 0.f;
#pragma unroll
            for (int j = 0; j < 12; j++) {
                sr += Ds[rr][j]      * kv[j];
                si += Ds[rr][12 + j] * kv[j];
            }
            yhb[(size_t)(t0 + rr) * 2048 + nio] = pack2bf(sr, si);
        }
    }
}

// ---------------------------------------------------------------------------
// Fused beta-contraction + bf16 A-fragment pack. Xfb is Hermitian-half:
// rows ma 0..15 stored; ma>=17 read as conj(Xf[32-ma][(32-ng)&31]).
// Grid: (ma 32) x (zig 64) = 2048 blocks; thread = (zil 2, lq 4, ng 32).
// R9: b-loop grouped in beta-quads; wfT[bq][t][4] gives one float4 per
// (bq, l) instead of 4 scalar strided loads.
// ---------------------------------------------------------------------------
__global__ __launch_bounds__(256) void k_beta_A(const u32* __restrict__ Xfb,
                                                const float* __restrict__ wfT,
                                                u16* __restrict__ Ab) {
    int ma  = blockIdx.x >> 6;
    int zig = blockIdx.x & 63;
    int tid = threadIdx.x;
    int ng  = tid & 31;
    int lq  = (tid >> 5) & 3;
    int zil = tid >> 7;
    int zi  = zig * 2 + zil;
    int z = zi >> 5, i = zi & 31;
    int mh = (ma <= 15) ? ma : ma - 32;
    int nh = (ng <= 15) ? ng : ng - 32;
    int am = mh < 0 ? -mh : mh;
    int an = nh < 0 ? -nh : nh;
    int l0 = am > an ? am : an;
    int lb = lq * 4;

    int isconj = (ma > 16);
    int mau = isconj ? (32 - ma) : ma;
    int ngu = isconj ? ((32 - ng) & 31) : ng;
    if (mau > 15) { mau = 0; ngu = 0; }   // ma==16: l0==16, values unused

    int tl[4];
#pragma unroll
    for (int j = 0; j < 4; j++) {
        int l = lb + j;
        tl[j] = LB[l] + (mh + l) * (2 * l + 1) + (nh + l);
    }
    float2 acc[4];
#pragma unroll
    for (int j = 0; j < 4; j++) acc[j] = make_float2(0.f, 0.f);

    const u32* xp = Xfb + (size_t)zi * 32 * 512 + mau * 32 + ngu;
    float sgn = isconj ? -1.f : 1.f;
#pragma unroll 2
    for (int bq = 0; bq < 8; bq++) {
        u32 p0 = xp[(size_t)(4 * bq + 0) * 512];
        u32 p1 = xp[(size_t)(4 * bq + 1) * 512];
        u32 p2 = xp[(size_t)(4 * bq + 2) * 512];
        u32 p3 = xp[(size_t)(4 * bq + 3) * 512];
        float vx0 = __uint_as_float(p0 << 16);
        float vy0 = sgn * __uint_as_float(p0 & 0xffff0000u);
        float vx1 = __uint_as_float(p1 << 16);
        float vy1 = sgn * __uint_as_float(p1 & 0xffff0000u);
        float vx2 = __uint_as_float(p2 << 16);
        float vy2 = sgn * __uint_as_float(p2 & 0xffff0000u);
        float vx3 = __uint_as_float(p3 << 16);
        float vy3 = sgn * __uint_as_float(p3 & 0xffff0000u);
        const float4* wq = (const float4*)(wfT + (size_t)bq * (LTOT * 4));
#pragma unroll
        for (int j = 0; j < 4; j++) {
            if (lb + j >= l0) {
                float4 w = wq[tl[j]];
                acc[j].x += w.x * vx0 + w.y * vx1 + w.z * vx2 + w.w * vx3;
                acc[j].y += w.x * vy0 + w.y * vy1 + w.z * vy2 + w.w * vy3;
            }
        }
    }
    int s_i  = i >> 4;
    int kl   = 2 * (i & 15);
    int joff = kl & 7;
    int Lhi  = (kl >> 3) << 4;
#pragma unroll
    for (int j = 0; j < 4; j++) {
        int l = lb + j;
        if (l >= l0) {
            int mi = mh + l, ni = nh + l;
            int s   = 2 * ni + s_i;
            int row = 4 * mi + z;
            u32 pack = pack2bf(acc[j].x, acc[j].y);
            size_t off = (size_t)8192 * l * l + (size_t)s * 4096
                       + ((row >> 4) << 9) + ((Lhi + (row & 15)) << 3) + joff;
            *(u32*)(Ab + off) = pack;
        }
    }
}

// ---------------------------------------------------------------------------
// MFMA GEMM, R20: line-writer XCD grouping + distance-4 register pipeline.
// Grid 1024 (all co-resident, 4 blocks/CU). Within each aligned 32-id chunk:
//   o = id&31, g = o&7, k5 = o>>3;  work = (id&~31) | (g&3) | ((g>>2)<<4) | (k5<<2)
// Bijective; the 4 ids with equal g (differ by 8 -> SAME XCD) map to works
// at stride 4 = same (l, oq), n..n+3 = the 4 writers of each 64B zhT line.
// Work decode (big-l first): countdown over 4nl; n=rem>>2, oq=rem&3.
// Two named buffer pairs refill 4 steps ahead. S = 4l+2: peel(2) + l x 4
// covers all steps exactly (NO tail -- R17 lesson). NO LDS, NO barriers;
// fragment-ordered yhb uint4 B loads; per-lane perm+xor; unconditional
// tail prefetch (OOB stays inside 60MB ws; values dead).
// Output zh_T[zo][t] float pairs, plain stores (single buffer; R15/R16:
// scattered-store reductions are poison).
// ---------------------------------------------------------------------------
__global__ __launch_bounds__(256) void k_gemm(const u16* __restrict__ Ab,
                                              const u32* __restrict__ yhb,
                                              float* __restrict__ zhT) {
    int id  = (int)blockIdx.x;
    int o5  = id & 31;
    int g   = o5 & 7;
    int k5  = o5 >> 3;
    int flat = (id & ~31) | ((g & 3) + ((g >> 2) << 4) + (k5 << 2));
    int rem = flat, l, nl = 1;
    for (l = 15; l >= 0; l--) {
        nl = 2 * l + 1;
        int c = nl * 4;
        if (rem < c) break;
        rem -= c;
    }
    int n  = rem >> 2;
    int oq = rem & 3;
    int base = LB[l];
    const u16* Ag = Ab + (size_t)8192 * l * l;
    int S = 2 * nl;

    int tid = threadIdx.x, lane = tid & 63, w = tid >> 6;
    int cc = lane & 1;
    u32 sel = cc ? 0x01000302u : 0x03020100u;   // ror16 : identity
    u32 msk = cc ? 0u          : 0x80000000u;   // 0     : negate-hi

    const u32* Bb = yhb + (size_t)(base + n) * 2048 + (oq << 8) + ((lane >> 1) << 2);
    const u16* Aw = Ag + ((w << 10) | (lane << 3));

    floatx4 acc[2][2];
#pragma unroll
    for (int a = 0; a < 2; a++)
#pragma unroll
        for (int b = 0; b < 2; b++) acc[a][b] = (floatx4)0.f;

#define LOADB(s, q0, q1) { \
    const uint4* bp = (const uint4*)(Bb + (size_t)((s) >> 1) * nl * 2048 + (((s) & 1) << 10)); \
    q0 = bp[0]; q1 = bp[32]; }
#define LOADA(s, r0, r1) { \
    const u16* apx = Aw + (size_t)(s) * 4096; \
    r0 = *(const short8*)apx; r1 = *(const short8*)(apx + 512); }
#define MF(a, b, c) __builtin_amdgcn_mfma_f32_16x16x32_bf16(a, b, c, 0, 0, 0)
// compute 2 steps from a pair's regs, then refill that pair from step snew
#define COMP2REFILL(Bx0, Bx1, Ax0, Ax1, By0, By1, Ay0, Ay1, snew) { \
    short8 bf0 = btr4(Bx0, sel, msk), bf1 = btr4(Bx1, sel, msk); \
    short8 af0 = Ax0, af1 = Ax1; \
    short8 cf0 = btr4(By0, sel, msk), cf1 = btr4(By1, sel, msk); \
    short8 ag0 = Ay0, ag1 = Ay1; \
    LOADA(snew, Ax0, Ax1); LOADB(snew, Bx0, Bx1); \
    LOADA((snew) + 1, Ay0, Ay1); LOADB((snew) + 1, By0, By1); \
    acc[0][0] = MF(af0, bf0, acc[0][0]);  acc[1][0] = MF(af1, bf0, acc[1][0]); \
    acc[0][1] = MF(af0, bf1, acc[0][1]);  acc[1][1] = MF(af1, bf1, acc[1][1]); \
    acc[0][0] = MF(ag0, cf0, acc[0][0]);  acc[1][0] = MF(ag1, cf0, acc[1][0]); \
    acc[0][1] = MF(ag0, cf1, acc[0][1]);  acc[1][1] = MF(ag1, cf1, acc[1][1]); }

    // pair0 = steps s, s+1; pair1 = steps s+2, s+3
    uint4 p0B0, p0B1, p0C0, p0C1; short8 p0a0, p0a1, p0c0, p0c1;
    uint4 p1B0, p1B1, p1C0, p1C1; short8 p1a0, p1a1, p1c0, p1c1;
    LOADA(0, p0a0, p0a1); LOADB(0, p0B0, p0B1);
    LOADA(1, p0c0, p0c1); LOADB(1, p0C0, p0C1);
    LOADA(2, p1a0, p1a1); LOADB(2, p1B0, p1B1);
    LOADA(3, p1c0, p1c1); LOADB(3, p1C0, p1C1);

    // peel: steps 0,1. Then l iterations of 4 steps = 4l -> total 4l+2 = S.
    COMP2REFILL(p0B0, p0B1, p0a0, p0a1, p0C0, p0C1, p0c0, p0c1, 4);
    for (int s = 2; s + 2 < S; s += 4) {
        COMP2REFILL(p1B0, p1B1, p1a0, p1a1, p1C0, p1C1, p1c0, p1c1, s + 4);
        COMP2REFILL(p0B0, p0B1, p0a0, p0a1, p0C0, p0C1, p0c0, p0c1, s + 6);
    }
    // no tail: loop covers through step S-1 (R17's tail was a double-count)
#undef COMP2REFILL
#undef LOADB
#undef LOADA
#undef MF

    int q = lane >> 4, cn = lane & 15;
#pragma unroll
    for (int mt = 0; mt < 2; mt++) {
#pragma unroll
        for (int nt = 0; nt < 2; nt++) {
            int nu2 = (nt << 4) + cn;
            int o2  = (oq << 4) + (nu2 >> 1);
            int c2  = nu2 & 1;
#pragma unroll
            for (int r = 0; r < 4; r++) {
                int R = (w << 5) + (mt << 4) + (q << 2) + r;
                int m = R >> 2, z = R & 3;
                if (m < nl) {
                    int t  = base + m * nl + n;
                    int zo = (z << 6) + o2;
                    zhT[((size_t)zo * LTOT + t) * 2 + c2] = acc[mt][nt][r];
                }
            }
        }
    }
}

// ---------------------------------------------------------------------------
// Inverse, 4 betas per block. R14: packed-fp32 complex math throughout.
// gather: v_pk_fma broadcast MACs; pass 1: register twiddle rotation chains,
// zero twiddle LDS; pass 2: 135->15 LDS ops/task via chains + symmetries.
// Grid: 2048 = (bq 8) x (zo 256); 256 thr; ~17.7KB LDS.
// ---------------------------------------------------------------------------
__global__ __launch_bounds__(256, 8) void k_inv2(const float2* __restrict__ zhT,
                                                 const float* __restrict__ wiT,
                                                 const float* __restrict__ bias,
                                                 float* __restrict__ out) {
    __shared__ __align__(16) f32x2 Pb[4 * 544];  // plane p at p*544, rows stride 34
    __shared__ f32x2 Wf[32];                     // (cos, sin) 2pi i/32
    int tid = threadIdx.x;
    int zo = blockIdx.x & 255;
    int bq = blockIdx.x >> 8;
    int b0 = bq * 4;
    if (tid < 32) {
        float sv, cv;
        sincosf(6.28318530717958647692f * (float)tid / 32.0f, &sv, &cv);
        f32x2 wv; wv.x = cv; wv.y = sv;
        Wf[tid] = wv;
    }
    // ---- gather: thread = (ng 32, rq 8); 2 ma-rows; 4 betas share each zv
    {
        int ng = tid & 31, rq = tid >> 5;
        int nh = (ng <= 15) ? ng : ng - 32;
        int an = nh < 0 ? -nh : nh;
        const f32x2* zr = (const f32x2*)zhT + (size_t)zo * LTOT;
        const f32x2* wp = (const f32x2*)wiT + (size_t)bq * (LTOT * 2);
#pragma unroll
        for (int mr = 0; mr < 2; mr++) {
            int ma = rq + 8 * mr;
            int l0 = ma > an ? ma : an;
            f32x2 a0 = (f32x2)0.f, a1 = a0, a2 = a0, a3 = a0;
#pragma unroll 4
            for (int l = 0; l < 16; l++) {
                if (l >= l0) {
                    int t = LB[l] + (ma + l) * (2 * l + 1) + (nh + l);
                    f32x2 zv = zr[t];
                    f32x2 w01 = wp[2 * t], w23 = wp[2 * t + 1];
                    a0 = fma_bl(w01, zv, a0);
                    a1 = fma_bh(w01, zv, a1);
                    a2 = fma_bl(w23, zv, a2);
                    a3 = fma_bh(w23, zv, a3);
                }
            }
            int po = ma * 34 + ng;
            Pb[po]            = a0;
            Pb[544 + po]      = a1;
            Pb[2 * 544 + po]  = a2;
            Pb[3 * 544 + po]  = a3;
        }
    }
    __syncthreads();
    // ---- pass 1 (ng -> g): 64 rows x 8 q = 512 tasks over 2 rounds.
#pragma unroll
    for (int it = 0; it < 2; it++) {
        int task = tid + it * 256;
        int rowid = task >> 3, q = task & 7;
        f32x2* prow = &Pb[(rowid >> 4) * 544 + (rowid & 15) * 34];
        const floatx4* prow4 = (const floatx4*)prow;
        floatx4 eo0 = prow4[0];
        f32x2 Ep; Ep.x = eo0.x; Ep.y = eo0.y;
        f32x2 Op; Op.x = eo0.z; Op.y = eo0.w;
        f32x2 En = (f32x2)0.f, On = (f32x2)0.f;
        f32x2 r = Wf[2 * q];
        f32x2 t = r;
#pragma unroll
        for (int h = 1; h < 16; h++) {
            floatx4 eo = prow4[h];
            f32x2 e; e.x = eo.x; e.y = eo.y;
            f32x2 o; o.x = eo.z; o.y = eo.w;
            if (h & 1) { En = cfma(e, t, En); On = cfma(o, t, On); }
            else       { Ep = cfma(e, t, Ep); Op = cfma(o, t, Op); }
            if (h < 15) t = cmulp(t, r);
        }
        f32x2 E0 = Ep + En, E1 = Ep - En;
        f32x2 O0 = Op + On, O1 = Op - On;
        f32x2 wq = Wf[q];
        f32x2 w0 = cmulp(O0, wq);
        f32x2 u1 = cmulp(O1, wq);
        f32x2 w1; w1.x = -u1.y; w1.y = u1.x;     // i * u1  (W^{q+8} = i W^q)
        prow[q]      = E0 + w0;
        prow[q + 16] = E0 - w0;
        prow[q + 8]  = E1 + w1;
        prow[q + 24] = E1 - w1;
    }
    __syncthreads();
    // ---- pass 2 (ma -> a): tasks (p, qa, g) x4 rounds; direct store + bias
    float bv = bias[zo & 63];
#pragma unroll
    for (int it = 0; it < 4; it++) {
        int task = tid + it * 256;
        int p = task >> 8, rr = task & 255;
        int qa = rr >> 5, g = rr & 31;
        const f32x2* pc = &Pb[p * 544];
        f32x2 r = Wf[2 * qa];
        f32x2 u = Wf[qa];
        f32x2 Uee = (f32x2)0.f, Ueo = Uee, Ve = Uee, Vo = Uee;
        f32x2 c0 = pc[g];
        {   // j = 0: odd column only
            f32x2 c1 = pc[34 + g];
            Ve = cfma(c1, u, Ve);
        }
        f32x2 t = r;
        u = cmulp(u, r);
#pragma unroll
        for (int j = 1; j < 8; j++) {
            f32x2 ce = pc[(2 * j) * 34 + g];
            f32x2 co = pc[(2 * j + 1) * 34 + g];
            if (j & 1) { Ueo = cfma(ce, t, Ueo); Vo = cfma(co, u, Vo); }
            else       { Uee = cfma(ce, t, Uee); Ve = cfma(co, u, Ve); }
            if (j < 7) { t = cmulp(t, r); u = cmulp(u, r); }
        }
        float EaA = c0.x + 2.f * (Uee.x + Ueo.x);
        float EaB = c0.x + 2.f * (Uee.x - Ueo.x);
        float OaA = 2.f * (Ve.x + Vo.x);
        float OaB = -2.f * (Ve.y - Vo.y);
        float* dst = out + (size_t)zo * 32768 + (size_t)(b0 + p) * 1024;
        constexpr float sc = 1.f / 1024.f;
        dst[qa * 32 + g]         = (EaA + OaA) * sc + bv;
        dst[(qa + 16) * 32 + g]  = (EaA - OaA) * sc + bv;
        dst[(qa + 8) * 32 + g]   = (EaB + OaB) * sc + bv;
        dst[(qa + 24) * 32 + g]  = (EaB - OaB) * sc + bv;
    }
}

// ---------------------------------------------------------------------------
extern "C" void kernel_launch(void* const* d_in, const int* in_sizes, int n_in,
                              void* d_out, int out_size, void* d_ws, size_t ws_size,
                              hipStream_t stream) {
    const float* x    = (const float*)d_in[0];
    const float* ker  = (const float*)d_in[1];
    const float* bias = (const float*)d_in[2];
    const float* wf   = (const float*)d_in[3];
    const float* wi   = (const float*)d_in[4];
    const float* Dre  = (const float*)d_in[5];
    const float* Dim  = (const float*)d_in[6];
    float* out = (float*)d_out;

    // layout: yhb 44.7MB | Ab 4.2MB | zh_T 11.2MB.
    // Xfb (8.4MB) + wfT (698KB, at zhT+8.39MB) alias zh_T: both dead once
    // k_gemm writes zhT. wiT (698KB) aliases yhb base: written after k_gemm
    // (yhb dead), read by k_inv2.
    char* ws = (char*)d_ws;
    u32*    yhb = (u32*)ws;
    u16*    Ab  = (u16*)(ws + 44695552);
    float*  zhT = (float*)(ws + 44695552 + 4194304);
    u32*    Xfb = (u32*)zhT;                                    // disjoint lifetime vs zh_T
    float*  wfT = (float*)(ws + 44695552 + 4194304 + 8388608);  // zhT tail, pre-gemm
    float*  wiT = (float*)ws;                                   // yhb region, post-gemm

    hipLaunchKernelGGL(k_fft_fwd, dim3(4096),  dim3(512), 0, stream, x, Xfb);
    hipLaunchKernelGGL(k_wtr,     dim3(22, 8), dim3(256), 0, stream, wf, wfT);
    hipLaunchKernelGGL(k_prep_B,  dim3(2728),  dim3(256), 0, stream, Dre, Dim, ker, yhb);
    hipLaunchKernelGGL(k_beta_A,  dim3(2048),  dim3(256), 0, stream, Xfb, wfT, Ab);
    hipLaunchKernelGGL(k_gemm,    dim3(1024),  dim3(256), 0, stream, Ab, yhb, zhT);
    hipLaunchKernelGGL(k_wtr,     dim3(22, 8), dim3(256), 0, stream, wi, wiT);
    hipLaunchKernelGGL(k_inv2,    dim3(2048),  dim3(256), 0, stream,
                       (const float2*)zhT, wiT, bias, out);
}

// Round 14
// 192.999 us; speedup vs baseline: 1.0765x; 1.0399x over previous
//
#include <hip/hip_runtime.h>
#include <math.h>

// ---------------------------------------------------------------------------
// SO3 convolution. bf16 MFMA GEMM (complex-as-real); Hermitian-half FFT/IFFT.
// Pipeline: k_fft_fwd -> k_wtr(wf) -> k_prep_B -> k_beta_A
//           -> k_gemm (MFMA) -> k_wtr(wi) -> k_inv2
// R8: fusing fft+prep spilled -- keep kernels separate.
// R9: wfT/wiT [bq][t][4] transposes. R10: k_inv2 streamed (8 blk/CU).
// R12: yhb in MFMA-fragment order; k_gemm no-LDS no-barrier. R13: o-quarter
// split. R14: packed-fp32 complex + register twiddle chains (inv2, then fft
// in R21). R15/R16: scattered-store reductions are poison in ANY form.
// R17 BROKEN (tail double-count). R18 distance-4: NEUTRAL. R19/R20 placement
// swizzles: ~neutral (R20 kept). R21 front-half (fft packed, prep_B x4
// occupancy): -1.3us only -> budget re-audit: harness re-poison fill (268MB,
// ~43us) is inside the measured window; our kernels ~157us.
// R22: k_gemm traffic audit: per 2-step group each block pulls A 16KB +
// B 8KB through L1 = ~30 B/cy/CU at 4 blk/CU -- 3x the ~10 B/cy per-CU
// load-return ceiling => L1-PORT-bound (explains R18/R19/R20 neutrality).
// B is 4x-redundant across waves (Bb w-independent) -> stage B via LDS:
// 128 thr load 128 uint4/group once, 1 barrier/group, waves ds_read frags.
// Per-group L1 bytes 24->18KB (-25%). A stays in register pipeline.
// Workspace: yhb 44.7MB | Ab 4.2MB | zh_T 11.2MB.
//   Xfb (8.4MB) + wfT (698KB) alias zh_T (lifetime fft->gemm, disjoint).
//   wiT (698KB) aliases yhb base (written after gemm, read by inv2).
// ---------------------------------------------------------------------------

typedef unsigned short u16;
typedef unsigned int   u32;
typedef __attribute__((ext_vector_type(8))) short  short8;   // 8 bf16
typedef __attribute__((ext_vector_type(4))) float  floatx4;
typedef __attribute__((ext_vector_type(2))) float  f32x2;

constexpr int LTOT = 5456;

constexpr int LB[17] = {0,1,10,35,84,165,286,455,680,969,
                        1330,1771,2300,2925,3654,4495,5456};

__device__ inline u16 f2bf(float f) {
    u32 u = __float_as_uint(f);
    u += 0x7fff + ((u >> 16) & 1);
    return (u16)(u >> 16);
}
__device__ inline u32 pack2bf(float re, float im) {
    return (u32)f2bf(re) | ((u32)f2bf(im) << 16);
}

// cc-dependent complex pack transform: cc=0 -> (re,-im) == b ^ 0x80000000;
// cc=1 -> (im,re) == ror16(b). Done as per-lane-constant perm + xor.
__device__ inline short8 btr4(uint4 q, u32 sel, u32 msk) {
    uint4 t;
    t.x = __builtin_amdgcn_perm(q.x, q.x, sel) ^ msk;
    t.y = __builtin_amdgcn_perm(q.y, q.y, sel) ^ msk;
    t.z = __builtin_amdgcn_perm(q.z, q.z, sel) ^ msk;
    t.w = __builtin_amdgcn_perm(q.w, q.w, sel) ^ msk;
    return *(short8*)&t;
}

// ---- packed-fp32 complex helpers (VOP3P). acc/result = (re, im) pairs. ----
__device__ __forceinline__ f32x2 cfma(f32x2 e, f32x2 t, f32x2 acc) {
    asm("v_pk_fma_f32 %0, %1, %2, %0 op_sel:[0,0,0] op_sel_hi:[0,1,1]\n\t"
        "v_pk_fma_f32 %0, %1, %2, %0 op_sel:[1,1,0] op_sel_hi:[1,0,1] neg_lo:[0,1,0]"
        : "+v"(acc) : "v"(e), "v"(t));
    return acc;
}
__device__ __forceinline__ f32x2 cmulp(f32x2 t, f32x2 r) {
    f32x2 d;
    asm("v_pk_mul_f32 %0, %1, %2 op_sel:[0,0] op_sel_hi:[0,1]\n\t"
        "v_pk_fma_f32 %0, %1, %2, %0 op_sel:[1,1,0] op_sel_hi:[1,0,1] neg_lo:[0,1,0]"
        : "=&v"(d) : "v"(t), "v"(r));
    return d;
}
__device__ __forceinline__ f32x2 fma_bl(f32x2 w2, f32x2 v, f32x2 acc) {
    asm("v_pk_fma_f32 %0, %1, %2, %0 op_sel:[0,0,0] op_sel_hi:[0,1,1]"
        : "+v"(acc) : "v"(w2), "v"(v));
    return acc;
}
__device__ __forceinline__ f32x2 fma_bh(f32x2 w2, f32x2 v, f32x2 acc) {
    asm("v_pk_fma_f32 %0, %1, %2, %0 op_sel:[1,0,0] op_sel_hi:[1,1,1]"
        : "+v"(acc) : "v"(w2), "v"(v));
    return acc;
}

// ---------------------------------------------------------------------------
// Wigner-table transpose: w[32][LTOT] -> wT[bq(8)][t][4] so a 4-beta group is
// one float4. Grid (22, 8) x 256.
// ---------------------------------------------------------------------------
__global__ __launch_bounds__(256) void k_wtr(const float* __restrict__ w,
                                             float* __restrict__ wT) {
    int t  = blockIdx.x * 256 + threadIdx.x;
    int bq = blockIdx.y;
    if (t < LTOT) {
        float4 v;
        v.x = w[(size_t)(bq * 4 + 0) * LTOT + t];
        v.y = w[(size_t)(bq * 4 + 1) * LTOT + t];
        v.z = w[(size_t)(bq * 4 + 2) * LTOT + t];
        v.w = w[(size_t)(bq * 4 + 3) * LTOT + t];
        *(float4*)(wT + ((size_t)bq * LTOT + t) * 4) = v;
    }
}

// ---------------------------------------------------------------------------
// Forward FFT2 (e^{-i}), R21: packed-complex. 512 threads.
// ---------------------------------------------------------------------------
__global__ __launch_bounds__(512) void k_fft_fwd(const float* __restrict__ x,
                                                 u32* __restrict__ Xfb) {
    __shared__ __align__(8) float xs[1088];    // [a][g] stride 34 (8B-aligned rows)
    __shared__ __align__(8) f32x2 Gc[1056];    // [a][k] stride 33, (re,im)
    __shared__ f32x2 Wfc[32];                  // (cos, -sin): conj table
    int tid = threadIdx.x;
    if (tid < 32) {
        float sv, cv;
        sincosf(6.28318530717958647692f * (float)tid / 32.0f, &sv, &cv);
        f32x2 wv; wv.x = cv; wv.y = -sv;
        Wfc[tid] = wv;
    }
    const float* src = x + (size_t)blockIdx.x * 1024;
    for (int e = tid; e < 1024; e += 512) xs[(e >> 5) * 34 + (e & 31)] = src[e];
    __syncthreads();
    // pass 1: E += xe*conj(W)^{2hk}, O += xo*conj(W)^{2hk}; out k, k+16
    {
        int a = tid >> 4, k = tid & 15;
        const f32x2* rowp = (const f32x2*)&xs[a * 34];
        f32x2 r = Wfc[2 * k];
        f32x2 p0 = rowp[0];
        f32x2 E; E.x = p0.x; E.y = 0.f;
        f32x2 O; O.x = p0.y; O.y = 0.f;
        f32x2 t = r;
#pragma unroll
        for (int h = 1; h < 16; h++) {
            f32x2 p = rowp[h];               // (xe, xo)
            E = fma_bl(p, t, E);             // E += xe * t
            O = fma_bh(p, t, O);             // O += xo * t
            if (h < 15) t = cmulp(t, r);
        }
        f32x2 WO = cmulp(O, Wfc[k]);         // O * conj(W^k)
        Gc[a * 33 + k]      = E + WO;
        Gc[a * 33 + k + 16] = E - WO;
    }
    __syncthreads();
    // pass 2: E += e*conj(W)^{2h*ma}; store row ma (0..15)
    {
        u32* dst = Xfb + (size_t)blockIdx.x * 512;
        int ng = tid & 31, ma = tid >> 5;
        f32x2 r = Wfc[2 * ma];
        f32x2 E = Gc[ng];                    // a = 0
        f32x2 O = Gc[33 + ng];               // a = 1
        f32x2 t = r;
#pragma unroll
        for (int h = 1; h < 16; h++) {
            f32x2 e = Gc[(2 * h) * 33 + ng];
            f32x2 o = Gc[(2 * h + 1) * 33 + ng];
            E = cfma(e, t, E);
            O = cfma(o, t, O);
            if (h < 15) t = cmulp(t, r);
        }
        f32x2 WO = cmulp(O, Wfc[ma]);
        dst[ma * 32 + ng] = pack2bf(E.x + WO.x, E.y + WO.y);
    }
}

// ---------------------------------------------------------------------------
// Build compact bf16 yh in MFMA-FRAGMENT ORDER (R12). R21: 2 t-rows/block.
// ---------------------------------------------------------------------------
__global__ __launch_bounds__(256) void k_prep_B(const float* __restrict__ Dre,
                                                const float* __restrict__ Dim,
                                                const float* __restrict__ ker,
                                                u32* __restrict__ yhb) {
    __shared__ float Ds[2][24];
    int t0  = blockIdx.x * 2;
    int tid = threadIdx.x;
    if (tid < 48) {
        int rr = tid / 24, jj = tid - rr * 24;
        Ds[rr][jj] = (jj < 12) ? Dre[(t0 + rr) * 12 + jj] : Dim[(t0 + rr) * 12 + jj - 12];
    }
    __syncthreads();
    for (int rep = 0; rep < 8; rep++) {
        int io = rep * 256 + tid;
        int i  = io >> 6, o = io & 63;
        int nio = ((i >> 4) << 10) + ((o >> 5) << 9) + (((o >> 3) & 3) << 7)
                + (((i >> 2) & 3) << 5) + ((o & 7) << 2) + (i & 3);
        const float4* kp = (const float4*)(ker + io * 12);
        float4 ka = kp[0], kb = kp[1], kc = kp[2];
        float kv[12] = {ka.x, ka.y, ka.z, ka.w, kb.x, kb.y, kb.z, kb.w,
                        kc.x, kc.y, kc.z, kc.w};
#pragma unroll
        for (int rr = 0; rr < 2; rr++) {
            float sr = 0.f, si = 0.f;
#pragma unroll
            for (int j = 0; j < 12; j++) {
                sr += Ds[rr][j]      * kv[j];
                si += Ds[rr][12 + j] * kv[j];
            }
            yhb[(size_t)(t0 + rr) * 2048 + nio] = pack2bf(sr, si);
        }
    }
}

// ---------------------------------------------------------------------------
// Fused beta-contraction + bf16 A-fragment pack (R9 wfT float4 loads).
// ---------------------------------------------------------------------------
__global__ __launch_bounds__(256) void k_beta_A(const u32* __restrict__ Xfb,
                                                const float* __restrict__ wfT,
                                                u16* __restrict__ Ab) {
    int ma  = blockIdx.x >> 6;
    int zig = blockIdx.x & 63;
    int tid = threadIdx.x;
    int ng  = tid & 31;
    int lq  = (tid >> 5) & 3;
    int zil = tid >> 7;
    int zi  = zig * 2 + zil;
    int z = zi >> 5, i = zi & 31;
    int mh = (ma <= 15) ? ma : ma - 32;
    int nh = (ng <= 15) ? ng : ng - 32;
    int am = mh < 0 ? -mh : mh;
    int an = nh < 0 ? -nh : nh;
    int l0 = am > an ? am : an;
    int lb = lq * 4;

    int isconj = (ma > 16);
    int mau = isconj ? (32 - ma) : ma;
    int ngu = isconj ? ((32 - ng) & 31) : ng;
    if (mau > 15) { mau = 0; ngu = 0; }   // ma==16: l0==16, values unused

    int tl[4];
#pragma unroll
    for (int j = 0; j < 4; j++) {
        int l = lb + j;
        tl[j] = LB[l] + (mh + l) * (2 * l + 1) + (nh + l);
    }
    float2 acc[4];
#pragma unroll
    for (int j = 0; j < 4; j++) acc[j] = make_float2(0.f, 0.f);

    const u32* xp = Xfb + (size_t)zi * 32 * 512 + mau * 32 + ngu;
    float sgn = isconj ? -1.f : 1.f;
#pragma unroll 2
    for (int bq = 0; bq < 8; bq++) {
        u32 p0 = xp[(size_t)(4 * bq + 0) * 512];
        u32 p1 = xp[(size_t)(4 * bq + 1) * 512];
        u32 p2 = xp[(size_t)(4 * bq + 2) * 512];
        u32 p3 = xp[(size_t)(4 * bq + 3) * 512];
        float vx0 = __uint_as_float(p0 << 16);
        float vy0 = sgn * __uint_as_float(p0 & 0xffff0000u);
        float vx1 = __uint_as_float(p1 << 16);
        float vy1 = sgn * __uint_as_float(p1 & 0xffff0000u);
        float vx2 = __uint_as_float(p2 << 16);
        float vy2 = sgn * __uint_as_float(p2 & 0xffff0000u);
        float vx3 = __uint_as_float(p3 << 16);
        float vy3 = sgn * __uint_as_float(p3 & 0xffff0000u);
        const float4* wq = (const float4*)(wfT + (size_t)bq * (LTOT * 4));
#pragma unroll
        for (int j = 0; j < 4; j++) {
            if (lb + j >= l0) {
                float4 w = wq[tl[j]];
                acc[j].x += w.x * vx0 + w.y * vx1 + w.z * vx2 + w.w * vx3;
                acc[j].y += w.x * vy0 + w.y * vy1 + w.z * vy2 + w.w * vy3;
            }
        }
    }
    int s_i  = i >> 4;
    int kl   = 2 * (i & 15);
    int joff = kl & 7;
    int Lhi  = (kl >> 3) << 4;
#pragma unroll
    for (int j = 0; j < 4; j++) {
        int l = lb + j;
        if (l >= l0) {
            int mi = mh + l, ni = nh + l;
            int s   = 2 * ni + s_i;
            int row = 4 * mi + z;
            u32 pack = pack2bf(acc[j].x, acc[j].y);
            size_t off = (size_t)8192 * l * l + (size_t)s * 4096
                       + ((row >> 4) << 9) + ((Lhi + (row & 15)) << 3) + joff;
            *(u32*)(Ab + off) = pack;
        }
    }
}

// ---------------------------------------------------------------------------
// MFMA GEMM, R22: B staged via LDS (one barrier per 2-step group).
// Grid 1024 (4 blk/CU), R20 line-writer swizzle + decode (big-l countdown:
// n = rem>>2, oq = rem&3). Per group g (steps 2g,2g+1): 128 threads load the
// group's 128 unique uint4 of B once -> ds_write -> all 4 waves ds_read
// fragments (was 4x redundant global loads = the per-CU L1-port wall).
// A stays in a 1-group-ahead register pipeline (rows unique per wave).
// Race audit: single barrier/group: barrier(g) fences ds_writes(g-1) before
// reads(g), and reads of buf[(g+1)&1] (iter g-1) before its overwrite (g).
// Groups G = nl (odd): peel 1, then l x 2-unrolled. Unconditional tail
// loads stay inside allocated ws (verified: B max index < LTOT rows; A
// spills <=0.6MB into zhT region -- values dead).
// Output zh_T[zo][t] float pairs, plain stores (R15/R16: scattered-store
// reductions are poison).
// ---------------------------------------------------------------------------
__global__ __launch_bounds__(256) void k_gemm(const u16* __restrict__ Ab,
                                              const u32* __restrict__ yhb,
                                              float* __restrict__ zhT) {
    __shared__ __align__(16) uint4 Bs[2][128];   // [dbuf][step2*64 + u]

    int id  = (int)blockIdx.x;
    int o5  = id & 31;
    int g5  = o5 & 7;
    int k5  = o5 >> 3;
    int flat = (id & ~31) | ((g5 & 3) + ((g5 >> 2) << 4) + (k5 << 2));
    int rem = flat, l, nl = 1;
    for (l = 15; l >= 0; l--) {
        nl = 2 * l + 1;
        int c = nl * 4;
        if (rem < c) break;
        rem -= c;
    }
    int n  = rem >> 2;
    int oq = rem & 3;
    int base = LB[l];
    const u16* Ag = Ab + (size_t)8192 * l * l;
    int G = nl;                          // groups of 2 steps; S = 2*nl

    int tid = threadIdx.x, lane = tid & 63, w = tid >> 6;
    int cc = lane & 1;
    u32 sel = cc ? 0x01000302u : 0x03020100u;   // ror16 : identity
    u32 msk = cc ? 0u          : 0x80000000u;   // 0     : negate-hi

    const uint4* Bg = (const uint4*)yhb + (size_t)(base + n) * 512 + (oq << 6);
    const u16*   Aw = Ag + ((w << 10) | (lane << 3));
    int lu = tid & 63, lsl = tid >> 6;   // loader coords (tid < 128 active)

    floatx4 acc[2][2];
#pragma unroll
    for (int a = 0; a < 2; a++)
#pragma unroll
        for (int b = 0; b < 2; b++) acc[a][b] = (floatx4)0.f;

#define LOADBG(gg, br) { if (tid < 128) br = Bg[(size_t)(gg) * nl * 512 + (lsl << 8) + lu]; }
#define LOADA2(gg, r0, r1, r2, r3) { \
    const u16* apx = Aw + (size_t)(gg) * 8192; \
    r0 = *(const short8*)apx;          r1 = *(const short8*)(apx + 512); \
    r2 = *(const short8*)(apx + 4096); r3 = *(const short8*)(apx + 4608); }
#define MF(a, b, c) __builtin_amdgcn_mfma_f32_16x16x32_bf16(a, b, c, 0, 0, 0)
// one group: barrier; stage next-B; refill B regs (g+2) + A regs (g+2);
// compute 2 steps from Bs[buf] and the A locals.
#define GROUP(buf, A0r, A1r, A2r, A3r, gnext) { \
    __syncthreads(); \
    if (tid < 128) Bs[(buf) ^ 1][tid] = Br; \
    LOADBG(gnext, Br); \
    short8 la0 = A0r, la1 = A1r, la2 = A2r, la3 = A3r; \
    LOADA2(gnext, A0r, A1r, A2r, A3r); \
    uint4 q0 = Bs[buf][lane >> 1],       q1 = Bs[buf][32 + (lane >> 1)]; \
    uint4 q2 = Bs[buf][64 + (lane >> 1)], q3 = Bs[buf][96 + (lane >> 1)]; \
    short8 bf0 = btr4(q0, sel, msk), bf1 = btr4(q1, sel, msk); \
    short8 bf2 = btr4(q2, sel, msk), bf3 = btr4(q3, sel, msk); \
    acc[0][0] = MF(la0, bf0, acc[0][0]);  acc[1][0] = MF(la1, bf0, acc[1][0]); \
    acc[0][1] = MF(la0, bf1, acc[0][1]);  acc[1][1] = MF(la1, bf1, acc[1][1]); \
    acc[0][0] = MF(la2, bf2, acc[0][0]);  acc[1][0] = MF(la3, bf2, acc[1][0]); \
    acc[0][1] = MF(la2, bf3, acc[0][1]);  acc[1][1] = MF(la3, bf3, acc[1][1]); }

    uint4 Br;
    short8 e0, e1, e2, e3;   // A regs, even-slot groups
    short8 d0, d1, d2, d3;   // A regs, odd-slot groups
    // prologue: B(0) -> Bs[0]; B(1) -> Br; A(0) -> e*, A(1) -> d*
    LOADBG(0, Br);
    if (tid < 128) Bs[0][tid] = Br;
    LOADBG(1, Br);
    LOADA2(0, e0, e1, e2, e3);
    LOADA2(1, d0, d1, d2, d3);

    // peel g=0 (even, buf 0), then l iterations of {odd, even}
    GROUP(0, e0, e1, e2, e3, 2);
    for (int g = 1; g + 1 < G; g += 2) {
        GROUP(1, d0, d1, d2, d3, g + 2);
        GROUP(0, e0, e1, e2, e3, g + 3);
    }
#undef GROUP
#undef LOADBG
#undef LOADA2
#undef MF

    int q = lane >> 4, cn = lane & 15;
#pragma unroll
    for (int mt = 0; mt < 2; mt++) {
#pragma unroll
        for (int nt = 0; nt < 2; nt++) {
            int nu2 = (nt << 4) + cn;
            int o2  = (oq << 4) + (nu2 >> 1);
            int c2  = nu2 & 1;
#pragma unroll
            for (int r = 0; r < 4; r++) {
                int R = (w << 5) + (mt << 4) + (q << 2) + r;
                int m = R >> 2, z = R & 3;
                if (m < nl) {
                    int t  = base + m * nl + n;
                    int zo = (z << 6) + o2;
                    zhT[((size_t)zo * LTOT + t) * 2 + c2] = acc[mt][nt][r];
                }
            }
        }
    }
}

// ---------------------------------------------------------------------------
// Inverse, 4 betas per block. R14: packed-fp32 complex math + register
// twiddle chains. Grid: 2048 = (bq 8) x (zo 256); 256 thr; ~17.7KB LDS.
// ---------------------------------------------------------------------------
__global__ __launch_bounds__(256, 8) void k_inv2(const float2* __restrict__ zhT,
                                                 const float* __restrict__ wiT,
                                                 const float* __restrict__ bias,
                                                 float* __restrict__ out) {
    __shared__ __align__(16) f32x2 Pb[4 * 544];  // plane p at p*544, rows stride 34
    __shared__ f32x2 Wf[32];                     // (cos, sin) 2pi i/32
    int tid = threadIdx.x;
    int zo = blockIdx.x & 255;
    int bq = blockIdx.x >> 8;
    int b0 = bq * 4;
    if (tid < 32) {
        float sv, cv;
        sincosf(6.28318530717958647692f * (float)tid / 32.0f, &sv, &cv);
        f32x2 wv; wv.x = cv; wv.y = sv;
        Wf[tid] = wv;
    }
    // ---- gather: thread = (ng 32, rq 8); 2 ma-rows; 4 betas share each zv
    {
        int ng = tid & 31, rq = tid >> 5;
        int nh = (ng <= 15) ? ng : ng - 32;
        int an = nh < 0 ? -nh : nh;
        const f32x2* zr = (const f32x2*)zhT + (size_t)zo * LTOT;
        const f32x2* wp = (const f32x2*)wiT + (size_t)bq * (LTOT * 2);
#pragma unroll
        for (int mr = 0; mr < 2; mr++) {
            int ma = rq + 8 * mr;
            int l0 = ma > an ? ma : an;
            f32x2 a0 = (f32x2)0.f, a1 = a0, a2 = a0, a3 = a0;
#pragma unroll 4
            for (int l = 0; l < 16; l++) {
                if (l >= l0) {
                    int t = LB[l] + (ma + l) * (2 * l + 1) + (nh + l);
                    f32x2 zv = zr[t];
                    f32x2 w01 = wp[2 * t], w23 = wp[2 * t + 1];
                    a0 = fma_bl(w01, zv, a0);
                    a1 = fma_bh(w01, zv, a1);
                    a2 = fma_bl(w23, zv, a2);
                    a3 = fma_bh(w23, zv, a3);
                }
            }
            int po = ma * 34 + ng;
            Pb[po]            = a0;
            Pb[544 + po]      = a1;
            Pb[2 * 544 + po]  = a2;
            Pb[3 * 544 + po]  = a3;
        }
    }
    __syncthreads();
    // ---- pass 1 (ng -> g): 64 rows x 8 q = 512 tasks over 2 rounds.
#pragma unroll
    for (int it = 0; it < 2; it++) {
        int task = tid + it * 256;
        int rowid = task >> 3, q = task & 7;
        f32x2* prow = &Pb[(rowid >> 4) * 544 + (rowid & 15) * 34];
        const floatx4* prow4 = (const floatx4*)prow;
        floatx4 eo0 = prow4[0];
        f32x2 Ep; Ep.x = eo0.x; Ep.y = eo0.y;
        f32x2 Op; Op.x = eo0.z; Op.y = eo0.w;
        f32x2 En = (f32x2)0.f, On = (f32x2)0.f;
        f32x2 r = Wf[2 * q];
        f32x2 t = r;
#pragma unroll
        for (int h = 1; h < 16; h++) {
            floatx4 eo = prow4[h];
            f32x2 e; e.x = eo.x; e.y = eo.y;
            f32x2 o; o.x = eo.z; o.y = eo.w;
            if (h & 1) { En = cfma(e, t, En); On = cfma(o, t, On); }
            else       { Ep = cfma(e, t, Ep); Op = cfma(o, t, Op); }
            if (h < 15) t = cmulp(t, r);
        }
        f32x2 E0 = Ep + En, E1 = Ep - En;
        f32x2 O0 = Op + On, O1 = Op - On;
        f32x2 wq = Wf[q];
        f32x2 w0 = cmulp(O0, wq);
        f32x2 u1 = cmulp(O1, wq);
        f32x2 w1; w1.x = -u1.y; w1.y = u1.x;     // i * u1  (W^{q+8} = i W^q)
        prow[q]      = E0 + w0;
        prow[q + 16] = E0 - w0;
        prow[q + 8]  = E1 + w1;
        prow[q + 24] = E1 - w1;
    }
    __syncthreads();
    // ---- pass 2 (ma -> a): tasks (p, qa, g) x4 rounds; direct store + bias
    float bv = bias[zo & 63];
#pragma unroll
    for (int it = 0; it < 4; it++) {
        int task = tid + it * 256;
        int p = task >> 8, rr = task & 255;
        int qa = rr >> 5, g = rr & 31;
        const f32x2* pc = &Pb[p * 544];
        f32x2 r = Wf[2 * qa];
        f32x2 u = Wf[qa];
        f32x2 Uee = (f32x2)0.f, Ueo = Uee, Ve = Uee, Vo = Uee;
        f32x2 c0 = pc[g];
        {   // j = 0: odd column only
            f32x2 c1 = pc[34 + g];
            Ve = cfma(c1, u, Ve);
        }
        f32x2 t = r;
        u = cmulp(u, r);
#pragma unroll
        for (int j = 1; j < 8; j++) {
            f32x2 ce = pc[(2 * j) * 34 + g];
            f32x2 co = pc[(2 * j + 1) * 34 + g];
            if (j & 1) { Ueo = cfma(ce, t, Ueo); Vo = cfma(co, u, Vo); }
            else       { Uee = cfma(ce, t, Uee); Ve = cfma(co, u, Ve); }
            if (j < 7) { t = cmulp(t, r); u = cmulp(u, r); }
        }
        float EaA = c0.x + 2.f * (Uee.x + Ueo.x);
        float EaB = c0.x + 2.f * (Uee.x - Ueo.x);
        float OaA = 2.f * (Ve.x + Vo.x);
        float OaB = -2.f * (Ve.y - Vo.y);
        float* dst = out + (size_t)zo * 32768 + (size_t)(b0 + p) * 1024;
        constexpr float sc = 1.f / 1024.f;
        dst[qa * 32 + g]         = (EaA + OaA) * sc + bv;
        dst[(qa + 16) * 32 + g]  = (EaA - OaA) * sc + bv;
        dst[(qa + 8) * 32 + g]   = (EaB + OaB) * sc + bv;
        dst[(qa + 24) * 32 + g]  = (EaB - OaB) * sc + bv;
    }
}

// ---------------------------------------------------------------------------
extern "C" void kernel_launch(void* const* d_in, const int* in_sizes, int n_in,
                              void* d_out, int out_size, void* d_ws, size_t ws_size,
                              hipStream_t stream) {
    const float* x    = (const float*)d_in[0];
    const float* ker  = (const float*)d_in[1];
    const float* bias = (const float*)d_in[2];
    const float* wf   = (const float*)d_in[3];
    const float* wi   = (const float*)d_in[4];
    const float* Dre  = (const float*)d_in[5];
    const float* Dim  = (const float*)d_in[6];
    float* out = (float*)d_out;

    // layout: yhb 44.7MB | Ab 4.2MB | zh_T 11.2MB.
    // Xfb (8.4MB) + wfT (698KB, at zhT+8.39MB) alias zh_T: both dead once
    // k_gemm writes zhT. wiT (698KB) aliases yhb base: written after k_gemm
    // (yhb dead), read by k_inv2.
    char* ws = (char*)d_ws;
    u32*    yhb = (u32*)ws;
    u16*    Ab  = (u16*)(ws + 44695552);
    float*  zhT = (float*)(ws + 44695552 + 4194304);
    u32*    Xfb = (u32*)zhT;                                    // disjoint lifetime vs zh_T
    float*  wfT = (float*)(ws + 44695552 + 4194304 + 8388608);  // zhT tail, pre-gemm
    float*  wiT = (float*)ws;                                   // yhb region, post-gemm

    hipLaunchKernelGGL(k_fft_fwd, dim3(4096),  dim3(512), 0, stream, x, Xfb);
    hipLaunchKernelGGL(k_wtr,     dim3(22, 8), dim3(256), 0, stream, wf, wfT);
    hipLaunchKernelGGL(k_prep_B,  dim3(2728),  dim3(256), 0, stream, Dre, Dim, ker, yhb);
    hipLaunchKernelGGL(k_beta_A,  dim3(2048),  dim3(256), 0, stream, Xfb, wfT, Ab);
    hipLaunchKernelGGL(k_gemm,    dim3(1024),  dim3(256), 0, stream, Ab, yhb, zhT);
    hipLaunchKernelGGL(k_wtr,     dim3(22, 8), dim3(256), 0, stream, wi, wiT);
    hipLaunchKernelGGL(k_inv2,    dim3(2048),  dim3(256), 0, stream,
                       (const float2*)zhT, wiT, bias, out);
}